// Round 9
// baseline (1732.738 us; speedup 1.0000x reference)
//
#include <hip/hip_runtime.h>
#include <math.h>

#define S_LEN 2048
#define NH 16
#define HDIM 64
#define BATCH 2
#define BHC 32          // BATCH*NH
#define KK 409          // int(2048 * (1.0 - 0.8)) per reference float math
#define DMODEL 1024

typedef __attribute__((ext_vector_type(8))) short bf16x8;   // 8 bf16 in 4 VGPRs
typedef __attribute__((ext_vector_type(4))) float f32x4;

// LDS-resident score matrix. 16 rows * 2052 * 4 B = 131,328 B -> 1 block/CU.
// 2052 % 32 == 4 -> no hot bank on any access pattern below.
#define SSTR 2052
#define T_STR  40       // bf16 LDS tile row stride for gemm: 80 B, 16B-aligned

__device__ __forceinline__ unsigned f2ord(float f) {
    unsigned u = __float_as_uint(f);
    return (u & 0x80000000u) ? ~u : (u | 0x80000000u);
}
__device__ __forceinline__ float ord2f(unsigned v) {
    unsigned u = (v & 0x80000000u) ? (v & 0x7fffffffu) : ~v;
    return __uint_as_float(u);
}
__device__ __forceinline__ unsigned short f2bf(float f) {   // RNE
    unsigned u = __float_as_uint(f);
    u += 0x7fffu + ((u >> 16) & 1u);
    return (unsigned short)(u >> 16);
}
__device__ __forceinline__ float bf2f(unsigned short h) {
    return __uint_as_float(((unsigned)h) << 16);
}

// ---------------------------------------------------------------------------
// fp32 -> bf16 hi/lo split (vectorized float4 / ushort4), n4 = elements/4
// ---------------------------------------------------------------------------
__global__ __launch_bounds__(256)
void split32(const float* __restrict__ in, unsigned short* __restrict__ hi,
             unsigned short* __restrict__ lo, int n4)
{
    const int i = blockIdx.x * 256 + threadIdx.x;
    if (i < n4) {
        const float4 v = ((const float4*)in)[i];
        ushort4 h, l;
        h.x = f2bf(v.x); l.x = f2bf(v.x - bf2f(h.x));
        h.y = f2bf(v.y); l.y = f2bf(v.y - bf2f(h.y));
        h.z = f2bf(v.z); l.z = f2bf(v.z - bf2f(h.z));
        h.w = f2bf(v.w); l.w = f2bf(v.w - bf2f(h.w));
        ((ushort4*)hi)[i] = h;
        ((ushort4*)lo)[i] = l;
    }
}

// ---------------------------------------------------------------------------
// LDS-staged split-bf16 3-pass MFMA GEMM (unchanged — R8 banked structure).
// ---------------------------------------------------------------------------
__global__ __launch_bounds__(256)
void gemm_mfma(const unsigned short* __restrict__ Ah, const unsigned short* __restrict__ Al,
               const unsigned short* __restrict__ Bh, const unsigned short* __restrict__ Bl,
               const float* __restrict__ bias, void* __restrict__ out0,
               void* __restrict__ out1, int mode)
{
    __shared__ __align__(16) unsigned short sAh[128 * T_STR];
    __shared__ __align__(16) unsigned short sAl[128 * T_STR];
    __shared__ __align__(16) unsigned short sBh[64 * T_STR];
    __shared__ __align__(16) unsigned short sBl[64 * T_STR];

    const int tid  = threadIdx.x;
    const int lane = tid & 63;
    const int w    = tid >> 6;
    const int q15  = lane & 15;
    const int quad = lane >> 4;
    const int n0b = blockIdx.x * 64;
    const int m0b = blockIdx.y * 128;
    const int wm = (w >> 1) * 64;
    const int wn = (w & 1) * 32;

    const int ar0 = tid >> 2, aks0 = (tid & 3) * 8;
    const int ar1 = (tid + 256) >> 2, aks1 = aks0;
    const int br = tid >> 2, bks = (tid & 3) * 8;

    const unsigned short* gAh0 = Ah + (size_t)(m0b + ar0) * 1024 + aks0;
    const unsigned short* gAh1 = Ah + (size_t)(m0b + ar1) * 1024 + aks1;
    const unsigned short* gAl0 = Al + (size_t)(m0b + ar0) * 1024 + aks0;
    const unsigned short* gAl1 = Al + (size_t)(m0b + ar1) * 1024 + aks1;
    const unsigned short* gBh = Bh + (size_t)(n0b + br) * 1024 + bks;
    const unsigned short* gBl = Bl + (size_t)(n0b + br) * 1024 + bks;

    f32x4 acc[4][2];
#pragma unroll
    for (int mt = 0; mt < 4; ++mt)
#pragma unroll
        for (int nt = 0; nt < 2; ++nt) acc[mt][nt] = (f32x4){0.f, 0.f, 0.f, 0.f};

#pragma unroll 1
    for (int k0 = 0; k0 < 1024; k0 += 32) {
        const bf16x8 vah0 = *(const bf16x8*)(gAh0 + k0);
        const bf16x8 vah1 = *(const bf16x8*)(gAh1 + k0);
        const bf16x8 val0 = *(const bf16x8*)(gAl0 + k0);
        const bf16x8 val1 = *(const bf16x8*)(gAl1 + k0);
        const bf16x8 vbh  = *(const bf16x8*)(gBh + k0);
        const bf16x8 vbl  = *(const bf16x8*)(gBl + k0);
        __syncthreads();
        *(bf16x8*)(sAh + ar0 * T_STR + aks0) = vah0;
        *(bf16x8*)(sAh + ar1 * T_STR + aks1) = vah1;
        *(bf16x8*)(sAl + ar0 * T_STR + aks0) = val0;
        *(bf16x8*)(sAl + ar1 * T_STR + aks1) = val1;
        *(bf16x8*)(sBh + br * T_STR + bks) = vbh;
        *(bf16x8*)(sBl + br * T_STR + bks) = vbl;
        __syncthreads();

        bf16x8 fbh[2], fbl[2];
#pragma unroll
        for (int nt = 0; nt < 2; ++nt) {
            fbh[nt] = *(const bf16x8*)(sBh + (wn + nt * 16 + q15) * T_STR + quad * 8);
            fbl[nt] = *(const bf16x8*)(sBl + (wn + nt * 16 + q15) * T_STR + quad * 8);
        }
#pragma unroll
        for (int mt = 0; mt < 4; ++mt) {
            const bf16x8 fah = *(const bf16x8*)(sAh + (wm + mt * 16 + q15) * T_STR + quad * 8);
            const bf16x8 fal = *(const bf16x8*)(sAl + (wm + mt * 16 + q15) * T_STR + quad * 8);
#pragma unroll
            for (int nt = 0; nt < 2; ++nt) {
                acc[mt][nt] = __builtin_amdgcn_mfma_f32_16x16x32_bf16(fah, fbh[nt], acc[mt][nt], 0, 0, 0);
                acc[mt][nt] = __builtin_amdgcn_mfma_f32_16x16x32_bf16(fah, fbl[nt], acc[mt][nt], 0, 0, 0);
                acc[mt][nt] = __builtin_amdgcn_mfma_f32_16x16x32_bf16(fal, fbh[nt], acc[mt][nt], 0, 0, 0);
            }
        }
    }

#pragma unroll
    for (int nt = 0; nt < 2; ++nt) {
        const int n = n0b + wn + nt * 16 + q15;
        const float bv = bias[n];
#pragma unroll
        for (int mt = 0; mt < 4; ++mt) {
            const int mb = m0b + wm + mt * 16 + quad * 4;
#pragma unroll
            for (int rg = 0; rg < 4; ++rg) {
                const int m = mb + rg;
                const float o = acc[mt][nt][rg] + bv;
                if (mode == 0) {
                    ((float*)out0)[(size_t)m * 1024 + n] = o;
                } else {
                    const int b = m >> 11, s = m & 2047;
                    const int h = n >> 6, hd = n & 63;
                    const size_t base = ((size_t)((b * NH + h) * S_LEN + s)) * HDIM + hd;
                    if (mode == 3) {
                        ((unsigned short*)out0)[base] = f2bf(o);
                    } else {
                        const unsigned short oh = f2bf(o);
                        ((unsigned short*)out0)[base] = oh;
                        ((unsigned short*)out1)[base] = f2bf(o - bf2f(oh));
                    }
                }
            }
        }
    }
}

// ---------------------------------------------------------------------------
// V bf16 [bh][s][64] -> Vt bf16 [bh][64][2048]
// ---------------------------------------------------------------------------
__global__ __launch_bounds__(256)
void transpose_v16(const unsigned short* __restrict__ V, unsigned short* __restrict__ Vt)
{
    __shared__ unsigned short t[64][72];
    const int tid = threadIdx.x;
    const int s0 = blockIdx.x * 64;
    const int bh = blockIdx.y;
    const unsigned short* Vb = V + (size_t)bh * S_LEN * HDIM;
#pragma unroll
    for (int i = 0; i < 4; ++i) {
        const int f = tid + i * 256;
        const int s = f >> 4;
        const int hq = (f & 15) * 4;
        const ushort4 v = *(const ushort4*)(Vb + (size_t)(s0 + s) * HDIM + hq);
        t[s][hq + 0] = v.x; t[s][hq + 1] = v.y; t[s][hq + 2] = v.z; t[s][hq + 3] = v.w;
    }
    __syncthreads();
    unsigned short* Vtb = Vt + (size_t)bh * HDIM * S_LEN;
#pragma unroll
    for (int i = 0; i < 4; ++i) {
        const int f = tid + i * 256;
        const int hd = f >> 4;
        const int sq = (f & 15) * 4;
        ushort4 v;
        v.x = t[sq + 0][hd]; v.y = t[sq + 1][hd];
        v.z = t[sq + 2][hd]; v.w = t[sq + 3][hd];
        *(ushort4*)(Vtb + (size_t)hd * S_LEN + s0 + sq) = v;
    }
}

__device__ __forceinline__ bf16x8 pack_hi8(const uint4 a0, const uint4 a1)
{
    union { unsigned u[4]; bf16x8 v; } c;
    c.u[0] = (a0.x >> 16) | (a0.y & 0xffff0000u);
    c.u[1] = (a0.z >> 16) | (a0.w & 0xffff0000u);
    c.u[2] = (a1.x >> 16) | (a1.y & 0xffff0000u);
    c.u[3] = (a1.z >> 16) | (a1.w & 0xffff0000u);
    return c.v;
}

// ---------------------------------------------------------------------------
// Shared helpers for both row_pass variants
// ---------------------------------------------------------------------------
#define TRP(AK, AKJ, J, M) { const unsigned _t = (((AK) >> (J)) ^ (AKJ)) & (M); \
                             (AK) ^= _t << (J); (AKJ) ^= _t; }
#define UMX(A, B) ((A) > (B) ? (A) : (B))

#define SELSTEP(TB, BITV) { \
    const unsigned eb = E & (TB); \
    const int cl = __builtin_popcount(eb); \
    int cnt = gcnt; \
    cnt += (int)__builtin_popcountll(__ballot(cl & 1)); \
    cnt += (int)__builtin_popcountll(__ballot(cl & 2)) << 1; \
    cnt += (int)__builtin_popcountll(__ballot(cl & 4)) << 2; \
    cnt += (int)__builtin_popcountll(__ballot(cl & 8)) << 3; \
    cnt += (int)__builtin_popcountll(__ballot(cl & 16)) << 4; \
    cnt += (int)__builtin_popcountll(__ballot(cl & 32)) << 5; \
    if (cnt >= KK) { T |= (BITV); E = eb; if (cnt == KK) goto sel_done; } \
    else { gcnt = cnt; E &= ~(TB); } \
}

#define MNU(U) { const unsigned _v = (U) >= T ? (U) : 0xffffffffu; mn = _v < mn ? _v : mn; }

#define EXG(UA, UB, UC, UD, OFF) { \
    const float ea = (UA) >= T ? __expf(ord2f(UA) - mx) : 0.f; \
    const float eb_ = (UB) >= T ? __expf(ord2f(UB) - mx) : 0.f; \
    const float ec = (UC) >= T ? __expf(ord2f(UC) - mx) : 0.f; \
    const float ed = (UD) >= T ? __expf(ord2f(UD) - mx) : 0.f; \
    uint4 wv; \
    wv.x = ((unsigned)f2bf(ea)) << 16; \
    wv.y = ((unsigned)f2bf(eb_)) << 16; \
    wv.z = ((unsigned)f2bf(ec)) << 16; \
    wv.w = ((unsigned)f2bf(ed)) << 16; \
    *(uint4*)(R + (OFF) + lane * 4) = wv; \
    lsum += ea + eb_ + ec + ed; }

#define ROW_LOAD_MAX \
    const uint4 q0 = *(const uint4*)(R + 0 * 256 + lane * 4); \
    const uint4 q1 = *(const uint4*)(R + 1 * 256 + lane * 4); \
    const uint4 q2 = *(const uint4*)(R + 2 * 256 + lane * 4); \
    const uint4 q3 = *(const uint4*)(R + 3 * 256 + lane * 4); \
    const uint4 q4 = *(const uint4*)(R + 4 * 256 + lane * 4); \
    const uint4 q5 = *(const uint4*)(R + 5 * 256 + lane * 4); \
    const uint4 q6 = *(const uint4*)(R + 6 * 256 + lane * 4); \
    const uint4 q7 = *(const uint4*)(R + 7 * 256 + lane * 4); \
    const unsigned u0  = q0.x, u1  = q0.y, u2  = q0.z, u3  = q0.w; \
    const unsigned u4  = q1.x, u5  = q1.y, u6  = q1.z, u7  = q1.w; \
    const unsigned u8  = q2.x, u9  = q2.y, u10 = q2.z, u11 = q2.w; \
    const unsigned u12 = q3.x, u13 = q3.y, u14 = q3.z, u15 = q3.w; \
    const unsigned u16 = q4.x, u17 = q4.y, u18 = q4.z, u19 = q4.w; \
    const unsigned u20 = q5.x, u21 = q5.y, u22 = q5.z, u23 = q5.w; \
    const unsigned u24 = q6.x, u25 = q6.y, u26 = q6.z, u27 = q6.w; \
    const unsigned u28 = q7.x, u29 = q7.y, u30 = q7.z, u31 = q7.w; \
    const unsigned a0 = UMX(u0, u1),  a1 = UMX(u2, u3),  a2 = UMX(u4, u5),  a3 = UMX(u6, u7); \
    const unsigned a4 = UMX(u8, u9),  a5 = UMX(u10, u11), a6 = UMX(u12, u13), a7 = UMX(u14, u15); \
    const unsigned a8 = UMX(u16, u17), a9 = UMX(u18, u19), a10 = UMX(u20, u21), a11 = UMX(u22, u23); \
    const unsigned a12 = UMX(u24, u25), a13 = UMX(u26, u27), a14 = UMX(u28, u29), a15 = UMX(u30, u31); \
    const unsigned b0 = UMX(a0, a1), b1 = UMX(a2, a3), b2 = UMX(a4, a5), b3 = UMX(a6, a7); \
    const unsigned b4 = UMX(a8, a9), b5 = UMX(a10, a11), b6 = UMX(a12, a13), b7 = UMX(a14, a15); \
    const unsigned c0 = UMX(b0, b1), c1 = UMX(b2, b3), c2 = UMX(b4, b5), c3 = UMX(b6, b7); \
    unsigned umx = UMX(UMX(c0, c1), UMX(c2, c3)); \
    _Pragma("unroll") \
    for (int off = 32; off >= 1; off >>= 1) { \
        const unsigned o = (unsigned)__shfl_xor((int)umx, off); \
        umx = o > umx ? o : umx; \
    } \
    const float mx = ord2f(umx);

#define ROW_TAIL \
    { \
        unsigned mn = 0xffffffffu; \
        MNU(u0) MNU(u1) MNU(u2) MNU(u3) MNU(u4) MNU(u5) MNU(u6) MNU(u7) \
        MNU(u8) MNU(u9) MNU(u10) MNU(u11) MNU(u12) MNU(u13) MNU(u14) MNU(u15) \
        MNU(u16) MNU(u17) MNU(u18) MNU(u19) MNU(u20) MNU(u21) MNU(u22) MNU(u23) \
        MNU(u24) MNU(u25) MNU(u26) MNU(u27) MNU(u28) MNU(u29) MNU(u30) MNU(u31) \
        _Pragma("unroll") \
        for (int off = 32; off >= 1; off >>= 1) { \
            const unsigned o = (unsigned)__shfl_xor((int)mn, off); \
            mn = o < mn ? o : mn; \
        } \
        T = mn; \
    } \
    float lsum = 0.f; \
    EXG(u0, u1, u2, u3, 0 * 256)    EXG(u4, u5, u6, u7, 1 * 256) \
    EXG(u8, u9, u10, u11, 2 * 256)  EXG(u12, u13, u14, u15, 3 * 256) \
    EXG(u16, u17, u18, u19, 4 * 256) EXG(u20, u21, u22, u23, 5 * 256) \
    EXG(u24, u25, u26, u27, 6 * 256) EXG(u28, u29, u30, u31, 7 * 256) \
    _Pragma("unroll") \
    for (int off = 32; off >= 1; off >>= 1) lsum += __shfl_xor(lsum, off); \
    return 1.f / lsum;

// ---------------------------------------------------------------------------
// row_pass (R12/R13 proven): bit-plane select, ~1500 instrs (fully unrolled)
// ---------------------------------------------------------------------------
__device__ __forceinline__ float row_pass(unsigned* R, const int lane)
{
    ROW_LOAD_MAX
    unsigned t0 = u0,  t1 = u1,  t2 = u2,  t3 = u3,  t4 = u4,  t5 = u5,  t6 = u6,  t7 = u7;
    unsigned t8 = u8,  t9 = u9,  t10 = u10, t11 = u11, t12 = u12, t13 = u13, t14 = u14, t15 = u15;
    unsigned t16 = u16, t17 = u17, t18 = u18, t19 = u19, t20 = u20, t21 = u21, t22 = u22, t23 = u23;
    unsigned t24 = u24, t25 = u25, t26 = u26, t27 = u27, t28 = u28, t29 = u29, t30 = u30, t31 = u31;
    TRP(t0, t16, 16, 0x0000FFFFu) TRP(t1, t17, 16, 0x0000FFFFu)
    TRP(t2, t18, 16, 0x0000FFFFu) TRP(t3, t19, 16, 0x0000FFFFu)
    TRP(t4, t20, 16, 0x0000FFFFu) TRP(t5, t21, 16, 0x0000FFFFu)
    TRP(t6, t22, 16, 0x0000FFFFu) TRP(t7, t23, 16, 0x0000FFFFu)
    TRP(t8, t24, 16, 0x0000FFFFu) TRP(t9, t25, 16, 0x0000FFFFu)
    TRP(t10, t26, 16, 0x0000FFFFu) TRP(t11, t27, 16, 0x0000FFFFu)
    TRP(t12, t28, 16, 0x0000FFFFu) TRP(t13, t29, 16, 0x0000FFFFu)
    TRP(t14, t30, 16, 0x0000FFFFu) TRP(t15, t31, 16, 0x0000FFFFu)
    TRP(t0, t8, 8, 0x00FF00FFu)  TRP(t1, t9, 8, 0x00FF00FFu)
    TRP(t2, t10, 8, 0x00FF00FFu) TRP(t3, t11, 8, 0x00FF00FFu)
    TRP(t4, t12, 8, 0x00FF00FFu) TRP(t5, t13, 8, 0x00FF00FFu)
    TRP(t6, t14, 8, 0x00FF00FFu) TRP(t7, t15, 8, 0x00FF00FFu)
    TRP(t16, t24, 8, 0x00FF00FFu) TRP(t17, t25, 8, 0x00FF00FFu)
    TRP(t18, t26, 8, 0x00FF00FFu) TRP(t19, t27, 8, 0x00FF00FFu)
    TRP(t20, t28, 8, 0x00FF00FFu) TRP(t21, t29, 8, 0x00FF00FFu)
    TRP(t22, t30, 8, 0x00FF00FFu) TRP(t23, t31, 8, 0x00FF00FFu)
    TRP(t0, t4, 4, 0x0F0F0F0Fu)  TRP(t1, t5, 4, 0x0F0F0F0Fu)
    TRP(t2, t6, 4, 0x0F0F0F0Fu)  TRP(t3, t7, 4, 0x0F0F0F0Fu)
    TRP(t8, t12, 4, 0x0F0F0F0Fu) TRP(t9, t13, 4, 0x0F0F0F0Fu)
    TRP(t10, t14, 4, 0x0F0F0F0Fu) TRP(t11, t15, 4, 0x0F0F0F0Fu)
    TRP(t16, t20, 4, 0x0F0F0F0Fu) TRP(t17, t21, 4, 0x0F0F0F0Fu)
    TRP(t18, t22, 4, 0x0F0F0F0Fu) TRP(t19, t23, 4, 0x0F0F0F0Fu)
    TRP(t24, t28, 4, 0x0F0F0F0Fu) TRP(t25, t29, 4, 0x0F0F0F0Fu)
    TRP(t26, t30, 4, 0x0F0F0F0Fu) TRP(t27, t31, 4, 0x0F0F0F0Fu)
    TRP(t0, t2, 2, 0x33333333u)  TRP(t1, t3, 2, 0x33333333u)
    TRP(t4, t6, 2, 0x33333333u)  TRP(t5, t7, 2, 0x33333333u)
    TRP(t8, t10, 2, 0x33333333u) TRP(t9, t11, 2, 0x33333333u)
    TRP(t12, t14, 2, 0x33333333u) TRP(t13, t15, 2, 0x33333333u)
    TRP(t16, t18, 2, 0x33333333u) TRP(t17, t19, 2, 0x33333333u)
    TRP(t20, t22, 2, 0x33333333u) TRP(t21, t23, 2, 0x33333333u)
    TRP(t24, t26, 2, 0x33333333u) TRP(t25, t27, 2, 0x33333333u)
    TRP(t28, t30, 2, 0x33333333u) TRP(t29, t31, 2, 0x33333333u)
    TRP(t0, t1, 1, 0x55555555u)  TRP(t2, t3, 1, 0x55555555u)
    TRP(t4, t5, 1, 0x55555555u)  TRP(t6, t7, 1, 0x55555555u)
    TRP(t8, t9, 1, 0x55555555u)  TRP(t10, t11, 1, 0x55555555u)
    TRP(t12, t13, 1, 0x55555555u) TRP(t14, t15, 1, 0x55555555u)
    TRP(t16, t17, 1, 0x55555555u) TRP(t18, t19, 1, 0x55555555u)
    TRP(t20, t21, 1, 0x55555555u) TRP(t22, t23, 1, 0x55555555u)
    TRP(t24, t25, 1, 0x55555555u) TRP(t26, t27, 1, 0x55555555u)
    TRP(t28, t29, 1, 0x55555555u) TRP(t30, t31, 1, 0x55555555u)

    unsigned T = 0u, E = 0xffffffffu;
    int gcnt = 0;
    SELSTEP(t31, 1u << 31) SELSTEP(t30, 1u << 30) SELSTEP(t29, 1u << 29) SELSTEP(t28, 1u << 28)
    SELSTEP(t27, 1u << 27) SELSTEP(t26, 1u << 26) SELSTEP(t25, 1u << 25) SELSTEP(t24, 1u << 24)
    SELSTEP(t23, 1u << 23) SELSTEP(t22, 1u << 22) SELSTEP(t21, 1u << 21) SELSTEP(t20, 1u << 20)
    SELSTEP(t19, 1u << 19) SELSTEP(t18, 1u << 18) SELSTEP(t17, 1u << 17) SELSTEP(t16, 1u << 16)
    SELSTEP(t15, 1u << 15) SELSTEP(t14, 1u << 14) SELSTEP(t13, 1u << 13) SELSTEP(t12, 1u << 12)
    SELSTEP(t11, 1u << 11) SELSTEP(t10, 1u << 10) SELSTEP(t9, 1u << 9)   SELSTEP(t8, 1u << 8)
    SELSTEP(t7, 1u << 7)   SELSTEP(t6, 1u << 6)   SELSTEP(t5, 1u << 5)   SELSTEP(t4, 1u << 4)
    SELSTEP(t3, 1u << 3)   SELSTEP(t2, 1u << 2)   SELSTEP(t1, 1u << 1)   SELSTEP(t0, 1u)
sel_done: ;
    ROW_TAIL
}

// ---------------------------------------------------------------------------
// row_pass_loop: SAME semantics, small code (~400 instrs).  Rank-count
// binary search as a RUNTIME loop over bits; per step 32 register compares
// (named scalars — no arrays, no scratch) + 6-ballot exact wave sum.
// #pragma unroll 1 is load-bearing: keeps code small for the icache test.
// ---------------------------------------------------------------------------
__device__ __forceinline__ float row_pass_loop(unsigned* R, const int lane)
{
    ROW_LOAD_MAX
    unsigned T = 0u;
#pragma unroll 1
    for (int b = 31; b >= 0; --b) {
        const unsigned X = T | (1u << b);
        int c = (u0 >= X) + (u1 >= X) + (u2 >= X) + (u3 >= X)
              + (u4 >= X) + (u5 >= X) + (u6 >= X) + (u7 >= X)
              + (u8 >= X) + (u9 >= X) + (u10 >= X) + (u11 >= X)
              + (u12 >= X) + (u13 >= X) + (u14 >= X) + (u15 >= X)
              + (u16 >= X) + (u17 >= X) + (u18 >= X) + (u19 >= X)
              + (u20 >= X) + (u21 >= X) + (u22 >= X) + (u23 >= X)
              + (u24 >= X) + (u25 >= X) + (u26 >= X) + (u27 >= X)
              + (u28 >= X) + (u29 >= X) + (u30 >= X) + (u31 >= X);
        int cnt = 0;
        cnt += (int)__builtin_popcountll(__ballot(c & 1));
        cnt += (int)__builtin_popcountll(__ballot(c & 2)) << 1;
        cnt += (int)__builtin_popcountll(__ballot(c & 4)) << 2;
        cnt += (int)__builtin_popcountll(__ballot(c & 8)) << 3;
        cnt += (int)__builtin_popcountll(__ballot(c & 16)) << 4;
        cnt += (int)__builtin_popcountll(__ballot(c & 32)) << 5;
        if (cnt >= KK) { T = X; if (cnt == KK) break; }
    }
    ROW_TAIL
}

// ---------------------------------------------------------------------------
// Fused attention R15 — R13 structure, template-gated phases for ablation.
// MODE bits: 1=QK^T, 2=select, 4=PV, 8=use row_pass_loop.
// <7> = R13-proven full kernel (the REAL dispatch).
// ---------------------------------------------------------------------------
template<int MODE>
__global__ __launch_bounds__(1024, 4)
void attn_kernel(const unsigned short* __restrict__ Qh, const unsigned short* __restrict__ Ql,
                 const unsigned short* __restrict__ Kh, const unsigned short* __restrict__ Kl,
                 const unsigned short* __restrict__ Vt,
                 unsigned short* __restrict__ AOh, unsigned short* __restrict__ AOl)
{
    constexpr bool DO_QKT = (MODE & 1) != 0;
    constexpr bool DO_SEL = (MODE & 2) != 0;
    constexpr bool DO_PV  = (MODE & 4) != 0;
    constexpr bool LOOPSEL = (MODE & 8) != 0;

    extern __shared__ __align__(16) char smem[];
    unsigned* S = (unsigned*)smem;          // [16][SSTR] ord scores / bf16-P overlay
    float* Opart = (float*)smem;            // overlay [16][16][64] after PV reads done

    const int tid  = threadIdx.x;
    const int lane = tid & 63;
    const int w    = tid >> 6;              // 0..15
    const int q15  = lane & 15;
    const int quad = lane >> 4;

    const int blk = blockIdx.x;
    const int bh  = (blk & 7) * 4 + ((blk >> 3) & 3);
    const int q0  = (blk >> 5) * 16;

    if constexpr (DO_QKT) {
        const size_t qrow = ((size_t)bh * S_LEN + q0 + q15) * HDIM;
        const bf16x8 bqh0 = *(const bf16x8*)(Qh + qrow + quad * 8);
        const bf16x8 bqh1 = *(const bf16x8*)(Qh + qrow + 32 + quad * 8);
        const bf16x8 bql0 = *(const bf16x8*)(Ql + qrow + quad * 8);
        const bf16x8 bql1 = *(const bf16x8*)(Ql + qrow + 32 + quad * 8);
        const size_t kbase = (size_t)bh * S_LEN * HDIM;
#pragma unroll 4
        for (int t = 0; t < 8; ++t) {
            const int key = w * 128 + t * 16 + q15;
            const unsigned short* kh = Kh + kbase + (size_t)key * HDIM + quad * 8;
            const unsigned short* kl = Kl + kbase + (size_t)key * HDIM + quad * 8;
            const bf16x8 akh0 = *(const bf16x8*)(kh);
            const bf16x8 akh1 = *(const bf16x8*)(kh + 32);
            const bf16x8 akl0 = *(const bf16x8*)(kl);
            const bf16x8 akl1 = *(const bf16x8*)(kl + 32);
            f32x4 c = {0.f, 0.f, 0.f, 0.f};
            c = __builtin_amdgcn_mfma_f32_16x16x32_bf16(akh0, bqh0, c, 0, 0, 0);
            c = __builtin_amdgcn_mfma_f32_16x16x32_bf16(akh1, bqh1, c, 0, 0, 0);
            c = __builtin_amdgcn_mfma_f32_16x16x32_bf16(akh0, bql0, c, 0, 0, 0);
            c = __builtin_amdgcn_mfma_f32_16x16x32_bf16(akh1, bql1, c, 0, 0, 0);
            c = __builtin_amdgcn_mfma_f32_16x16x32_bf16(akl0, bqh0, c, 0, 0, 0);
            c = __builtin_amdgcn_mfma_f32_16x16x32_bf16(akl1, bqh1, c, 0, 0, 0);
            c = c * 0.125f;
            uint4 o;
            o.x = f2ord(c[0]); o.y = f2ord(c[1]); o.z = f2ord(c[2]); o.w = f2ord(c[3]);
            *(uint4*)(S + q15 * SSTR + w * 128 + t * 16 + quad * 4) = o;
        }
    }
    __syncthreads();

    float invd = 1.0f;
    if constexpr (DO_SEL) {
        if constexpr (LOOPSEL) invd = row_pass_loop(S + w * SSTR, lane);
        else                   invd = row_pass(S + w * SSTR, lane);
    }
    __syncthreads();

    if constexpr (DO_PV) {
        f32x4 oacc[4];
#pragma unroll
        for (int ht = 0; ht < 4; ++ht) oacc[ht] = (f32x4){0.f, 0.f, 0.f, 0.f};
        const size_t vtb = (size_t)bh * HDIM * S_LEN;
        const unsigned* Srow = S + q15 * SSTR;
#pragma unroll 2
        for (int ks = 0; ks < 4; ++ks) {
            const int key0 = w * 128 + ks * 32 + quad * 8;
            const uint4 a0 = *(const uint4*)(Srow + key0);
            const uint4 a1 = *(const uint4*)(Srow + key0 + 4);
            const bf16x8 ap = pack_hi8(a0, a1);
#pragma unroll
            for (int ht = 0; ht < 4; ++ht) {
                const int hd = ht * 16 + q15;
                const bf16x8 bv = *(const bf16x8*)(Vt + vtb + (size_t)hd * S_LEN + key0);
                oacc[ht] = __builtin_amdgcn_mfma_f32_16x16x32_bf16(ap, bv, oacc[ht], 0, 0, 0);
            }
        }
        __syncthreads();
#pragma unroll
        for (int ht = 0; ht < 4; ++ht)
#pragma unroll
            for (int rg = 0; rg < 4; ++rg)
                Opart[w * 1024 + (quad * 4 + rg) * 64 + ht * 16 + q15] = oacc[ht][rg];
    } else {
        __syncthreads();
    }
    __syncthreads();

    {
        float s = 0.f;
#pragma unroll
        for (int ww = 0; ww < 16; ++ww)
            s += Opart[ww * 1024 + w * 64 + lane];
        const int b = bh >> 4, h = bh & 15;
        const float o = s * invd;
        const size_t i = ((size_t)(b * S_LEN + q0 + w)) * DMODEL + h * HDIM + lane;
        const unsigned short oh = f2bf(o);
        AOh[i] = oh; AOl[i] = f2bf(o - bf2f(oh));
    }
}

// ---------------------------------------------------------------------------
extern "C" void kernel_launch(void* const* d_in, const int* in_sizes, int n_in,
                              void* d_out, int out_size, void* d_ws, size_t ws_size,
                              hipStream_t stream)
{
    const float* X  = (const float*)d_in[0];
    const float* Wq = (const float*)d_in[1];
    const float* bq = (const float*)d_in[2];
    const float* Wk = (const float*)d_in[3];
    const float* bk = (const float*)d_in[4];
    const float* Wv = (const float*)d_in[5];
    const float* bv = (const float*)d_in[6];
    const float* Wo = (const float*)d_in[7];
    const float* bo = (const float*)d_in[8];

    char* p = (char*)d_ws;
    const size_t NEL = (size_t)BHC * S_LEN * HDIM;   // 4,194,304
    unsigned short* Q16h = (unsigned short*)p; p += NEL * 2;
    unsigned short* Q16l = (unsigned short*)p; p += NEL * 2;
    unsigned short* K16h = (unsigned short*)p; p += NEL * 2;
    unsigned short* K16l = (unsigned short*)p; p += NEL * 2;
    unsigned short* Vb16 = (unsigned short*)p; p += NEL * 2;
    unsigned short* Vt16 = (unsigned short*)p; p += NEL * 2;
    unsigned short* Xh   = (unsigned short*)p; p += NEL * 2;
    unsigned short* Xl   = (unsigned short*)p; p += NEL * 2;
    unsigned short* AOh  = (unsigned short*)p; p += NEL * 2;
    unsigned short* AOl  = (unsigned short*)p; p += NEL * 2;
    unsigned short* Wqh  = (unsigned short*)p; p += DMODEL * DMODEL * 2;
    unsigned short* Wql  = (unsigned short*)p; p += DMODEL * DMODEL * 2;
    unsigned short* Wkh  = (unsigned short*)p; p += DMODEL * DMODEL * 2;
    unsigned short* Wkl  = (unsigned short*)p; p += DMODEL * DMODEL * 2;
    unsigned short* Wvh  = (unsigned short*)p; p += DMODEL * DMODEL * 2;
    unsigned short* Wvl  = (unsigned short*)p; p += DMODEL * DMODEL * 2;
    unsigned short* Woh  = (unsigned short*)p; p += DMODEL * DMODEL * 2;
    unsigned short* Wol  = (unsigned short*)p; p += DMODEL * DMODEL * 2;

    const int attn_lds = 16 * SSTR * 4;   // 131,328 B -> 1 block/CU
    hipFuncSetAttribute((const void*)attn_kernel<7>,
                        hipFuncAttributeMaxDynamicSharedMemorySize, attn_lds);
    hipFuncSetAttribute((const void*)attn_kernel<6>,
                        hipFuncAttributeMaxDynamicSharedMemorySize, attn_lds);
    hipFuncSetAttribute((const void*)attn_kernel<5>,
                        hipFuncAttributeMaxDynamicSharedMemorySize, attn_lds);
    hipFuncSetAttribute((const void*)attn_kernel<15>,
                        hipFuncAttributeMaxDynamicSharedMemorySize, attn_lds);

    const int X4 = (int)(NEL / 4);
    const int W4 = DMODEL * DMODEL / 4;

    // ---- input splits ----
    split32<<<(X4 + 255) / 256, 256, 0, stream>>>(X,  Xh,  Xl,  X4);
    split32<<<(W4 + 255) / 256, 256, 0, stream>>>(Wq, Wqh, Wql, W4);
    split32<<<(W4 + 255) / 256, 256, 0, stream>>>(Wk, Wkh, Wkl, W4);
    split32<<<(W4 + 255) / 256, 256, 0, stream>>>(Wv, Wvh, Wvl, W4);
    split32<<<(W4 + 255) / 256, 256, 0, stream>>>(Wo, Woh, Wol, W4);

    // ---- projections ----
    const dim3 ggrid(16, 32, 1);
    gemm_mfma<<<ggrid, 256, 0, stream>>>(Xh, Xl, Wqh, Wql, bq, Q16h, Q16l, 2);
    gemm_mfma<<<ggrid, 256, 0, stream>>>(Xh, Xl, Wkh, Wkl, bk, K16h, K16l, 2);
    gemm_mfma<<<ggrid, 256, 0, stream>>>(Xh, Xl, Wvh, Wvl, bv, Vb16, nullptr, 3);
    transpose_v16<<<dim3(32, 32, 1), 256, 0, stream>>>(Vb16, Vt16);

    // ---- INSTRUMENTATION (outputs overwritten by REAL below) ----
    // A: full baseline @2048   B: no-QK^T   C: no-select   E: loop-select full
    attn_kernel<7> <<<2048, 1024, attn_lds, stream>>>(Q16h, Q16l, K16h, K16l, Vt16, AOh, AOl);
    attn_kernel<6> <<<2048, 1024, attn_lds, stream>>>(Q16h, Q16l, K16h, K16l, Vt16, AOh, AOl);
    attn_kernel<5> <<<2048, 1024, attn_lds, stream>>>(Q16h, Q16l, K16h, K16l, Vt16, AOh, AOl);
    attn_kernel<15><<<2048, 1024, attn_lds, stream>>>(Q16h, Q16l, K16h, K16l, Vt16, AOh, AOl);

    // ---- REAL (R13-proven full kernel; overwrites every AO index) ----
    attn_kernel<7> <<<4096, 1024, attn_lds, stream>>>(Q16h, Q16l, K16h, K16l, Vt16, AOh, AOl);

    // ---- output projection ----
    gemm_mfma<<<ggrid, 256, 0, stream>>>(AOh, AOl, Woh, Wol, bo, d_out, nullptr, 0);
}

// Round 10
// 836.232 us; speedup vs baseline: 2.0721x; 2.0721x over previous
//
#include <hip/hip_runtime.h>
#include <math.h>

#define S_LEN 2048
#define NH 16
#define HDIM 64
#define BATCH 2
#define BHC 32          // BATCH*NH
#define KK 409          // int(2048 * (1.0 - 0.8)) per reference float math
#define DMODEL 1024

typedef __attribute__((ext_vector_type(8))) short bf16x8;   // 8 bf16 in 4 VGPRs
typedef __attribute__((ext_vector_type(4))) float f32x4;

// LDS-resident score matrix. 16 rows * 2052 * 4 B = 131,328 B -> 1 block/CU.
// 2052 % 32 == 4 -> no hot bank on any access pattern below.
#define SSTR 2052
#define T_STR  40       // bf16 LDS tile row stride for gemm: 80 B, 16B-aligned

__device__ __forceinline__ unsigned f2ord(float f) {
    unsigned u = __float_as_uint(f);
    return (u & 0x80000000u) ? ~u : (u | 0x80000000u);
}
__device__ __forceinline__ float ord2f(unsigned v) {
    unsigned u = (v & 0x80000000u) ? (v & 0x7fffffffu) : ~v;
    return __uint_as_float(u);
}
__device__ __forceinline__ unsigned short f2bf(float f) {   // RNE
    unsigned u = __float_as_uint(f);
    u += 0x7fffu + ((u >> 16) & 1u);
    return (unsigned short)(u >> 16);
}
__device__ __forceinline__ float bf2f(unsigned short h) {
    return __uint_as_float(((unsigned)h) << 16);
}

// ---------------------------------------------------------------------------
// fp32 -> bf16 hi/lo split (vectorized float4 / ushort4), n4 = elements/4
// ---------------------------------------------------------------------------
__global__ __launch_bounds__(256)
void split32(const float* __restrict__ in, unsigned short* __restrict__ hi,
             unsigned short* __restrict__ lo, int n4)
{
    const int i = blockIdx.x * 256 + threadIdx.x;
    if (i < n4) {
        const float4 v = ((const float4*)in)[i];
        ushort4 h, l;
        h.x = f2bf(v.x); l.x = f2bf(v.x - bf2f(h.x));
        h.y = f2bf(v.y); l.y = f2bf(v.y - bf2f(h.y));
        h.z = f2bf(v.z); l.z = f2bf(v.z - bf2f(h.z));
        h.w = f2bf(v.w); l.w = f2bf(v.w - bf2f(h.w));
        ((ushort4*)hi)[i] = h;
        ((ushort4*)lo)[i] = l;
    }
}

// ---------------------------------------------------------------------------
// LDS-staged split-bf16 3-pass MFMA GEMM (unchanged — R8 banked structure).
// ---------------------------------------------------------------------------
__global__ __launch_bounds__(256)
void gemm_mfma(const unsigned short* __restrict__ Ah, const unsigned short* __restrict__ Al,
               const unsigned short* __restrict__ Bh, const unsigned short* __restrict__ Bl,
               const float* __restrict__ bias, void* __restrict__ out0,
               void* __restrict__ out1, int mode)
{
    __shared__ __align__(16) unsigned short sAh[128 * T_STR];
    __shared__ __align__(16) unsigned short sAl[128 * T_STR];
    __shared__ __align__(16) unsigned short sBh[64 * T_STR];
    __shared__ __align__(16) unsigned short sBl[64 * T_STR];

    const int tid  = threadIdx.x;
    const int lane = tid & 63;
    const int w    = tid >> 6;
    const int q15  = lane & 15;
    const int quad = lane >> 4;
    const int n0b = blockIdx.x * 64;
    const int m0b = blockIdx.y * 128;
    const int wm = (w >> 1) * 64;
    const int wn = (w & 1) * 32;

    const int ar0 = tid >> 2, aks0 = (tid & 3) * 8;
    const int ar1 = (tid + 256) >> 2, aks1 = aks0;
    const int br = tid >> 2, bks = (tid & 3) * 8;

    const unsigned short* gAh0 = Ah + (size_t)(m0b + ar0) * 1024 + aks0;
    const unsigned short* gAh1 = Ah + (size_t)(m0b + ar1) * 1024 + aks1;
    const unsigned short* gAl0 = Al + (size_t)(m0b + ar0) * 1024 + aks0;
    const unsigned short* gAl1 = Al + (size_t)(m0b + ar1) * 1024 + aks1;
    const unsigned short* gBh = Bh + (size_t)(n0b + br) * 1024 + bks;
    const unsigned short* gBl = Bl + (size_t)(n0b + br) * 1024 + bks;

    f32x4 acc[4][2];
#pragma unroll
    for (int mt = 0; mt < 4; ++mt)
#pragma unroll
        for (int nt = 0; nt < 2; ++nt) acc[mt][nt] = (f32x4){0.f, 0.f, 0.f, 0.f};

#pragma unroll 1
    for (int k0 = 0; k0 < 1024; k0 += 32) {
        const bf16x8 vah0 = *(const bf16x8*)(gAh0 + k0);
        const bf16x8 vah1 = *(const bf16x8*)(gAh1 + k0);
        const bf16x8 val0 = *(const bf16x8*)(gAl0 + k0);
        const bf16x8 val1 = *(const bf16x8*)(gAl1 + k0);
        const bf16x8 vbh  = *(const bf16x8*)(gBh + k0);
        const bf16x8 vbl  = *(const bf16x8*)(gBl + k0);
        __syncthreads();
        *(bf16x8*)(sAh + ar0 * T_STR + aks0) = vah0;
        *(bf16x8*)(sAh + ar1 * T_STR + aks1) = vah1;
        *(bf16x8*)(sAl + ar0 * T_STR + aks0) = val0;
        *(bf16x8*)(sAl + ar1 * T_STR + aks1) = val1;
        *(bf16x8*)(sBh + br * T_STR + bks) = vbh;
        *(bf16x8*)(sBl + br * T_STR + bks) = vbl;
        __syncthreads();

        bf16x8 fbh[2], fbl[2];
#pragma unroll
        for (int nt = 0; nt < 2; ++nt) {
            fbh[nt] = *(const bf16x8*)(sBh + (wn + nt * 16 + q15) * T_STR + quad * 8);
            fbl[nt] = *(const bf16x8*)(sBl + (wn + nt * 16 + q15) * T_STR + quad * 8);
        }
#pragma unroll
        for (int mt = 0; mt < 4; ++mt) {
            const bf16x8 fah = *(const bf16x8*)(sAh + (wm + mt * 16 + q15) * T_STR + quad * 8);
            const bf16x8 fal = *(const bf16x8*)(sAl + (wm + mt * 16 + q15) * T_STR + quad * 8);
#pragma unroll
            for (int nt = 0; nt < 2; ++nt) {
                acc[mt][nt] = __builtin_amdgcn_mfma_f32_16x16x32_bf16(fah, fbh[nt], acc[mt][nt], 0, 0, 0);
                acc[mt][nt] = __builtin_amdgcn_mfma_f32_16x16x32_bf16(fah, fbl[nt], acc[mt][nt], 0, 0, 0);
                acc[mt][nt] = __builtin_amdgcn_mfma_f32_16x16x32_bf16(fal, fbh[nt], acc[mt][nt], 0, 0, 0);
            }
        }
    }

#pragma unroll
    for (int nt = 0; nt < 2; ++nt) {
        const int n = n0b + wn + nt * 16 + q15;
        const float bv = bias[n];
#pragma unroll
        for (int mt = 0; mt < 4; ++mt) {
            const int mb = m0b + wm + mt * 16 + quad * 4;
#pragma unroll
            for (int rg = 0; rg < 4; ++rg) {
                const int m = mb + rg;
                const float o = acc[mt][nt][rg] + bv;
                if (mode == 0) {
                    ((float*)out0)[(size_t)m * 1024 + n] = o;
                } else {
                    const int b = m >> 11, s = m & 2047;
                    const int h = n >> 6, hd = n & 63;
                    const size_t base = ((size_t)((b * NH + h) * S_LEN + s)) * HDIM + hd;
                    if (mode == 3) {
                        ((unsigned short*)out0)[base] = f2bf(o);
                    } else {
                        const unsigned short oh = f2bf(o);
                        ((unsigned short*)out0)[base] = oh;
                        ((unsigned short*)out1)[base] = f2bf(o - bf2f(oh));
                    }
                }
            }
        }
    }
}

// ---------------------------------------------------------------------------
// V bf16 [bh][s][64] -> Vt bf16 [bh][64][2048]
// ---------------------------------------------------------------------------
__global__ __launch_bounds__(256)
void transpose_v16(const unsigned short* __restrict__ V, unsigned short* __restrict__ Vt)
{
    __shared__ unsigned short t[64][72];
    const int tid = threadIdx.x;
    const int s0 = blockIdx.x * 64;
    const int bh = blockIdx.y;
    const unsigned short* Vb = V + (size_t)bh * S_LEN * HDIM;
#pragma unroll
    for (int i = 0; i < 4; ++i) {
        const int f = tid + i * 256;
        const int s = f >> 4;
        const int hq = (f & 15) * 4;
        const ushort4 v = *(const ushort4*)(Vb + (size_t)(s0 + s) * HDIM + hq);
        t[s][hq + 0] = v.x; t[s][hq + 1] = v.y; t[s][hq + 2] = v.z; t[s][hq + 3] = v.w;
    }
    __syncthreads();
    unsigned short* Vtb = Vt + (size_t)bh * HDIM * S_LEN;
#pragma unroll
    for (int i = 0; i < 4; ++i) {
        const int f = tid + i * 256;
        const int hd = f >> 4;
        const int sq = (f & 15) * 4;
        ushort4 v;
        v.x = t[sq + 0][hd]; v.y = t[sq + 1][hd];
        v.z = t[sq + 2][hd]; v.w = t[sq + 3][hd];
        *(ushort4*)(Vtb + (size_t)hd * S_LEN + s0 + sq) = v;
    }
}

__device__ __forceinline__ bf16x8 pack_hi8(const uint4 a0, const uint4 a1)
{
    union { unsigned u[4]; bf16x8 v; } c;
    c.u[0] = (a0.x >> 16) | (a0.y & 0xffff0000u);
    c.u[1] = (a0.z >> 16) | (a0.w & 0xffff0000u);
    c.u[2] = (a1.x >> 16) | (a1.y & 0xffff0000u);
    c.u[3] = (a1.z >> 16) | (a1.w & 0xffff0000u);
    return c.v;
}

// ---------------------------------------------------------------------------
// R16 phase-2 row pass — branchless, SALU-free select.
// (R15 totals-decomposition: select ~230us of 565 is the largest phase; its
//  ballot path = ~700 SALU ops + 32 data-dependent branches per row through
//  the ONE scalar unit per CU, shared by all 4 SIMDs.  16 waves * 700 SALU
//  ~ 4.7us/block of scalar issue + VALU->SALU hazards — invisible in
//  MfmaUtil/VALUBusy/HBM, matching the phantom wall of R10-R14.)
//
// SELSTEP_BL: per-lane popcount + 6x shfl_xor VALU wave-sum (ds_bpermute,
// LDS pipe) + v_cndmask updates.  Zero SALU ops, zero branches, fixed 32
// steps.  Semantics PROVEN identical to the R8..R13 rank-count select:
// completing all 32 bits converges T to the exact KK-th largest value
// (ties included); final min{u>=T} == T.  Early exit removed (it was a
// speed hack; without it the full search yields the same threshold).
// ---------------------------------------------------------------------------
#define TRP(AK, AKJ, J, M) { const unsigned _t = (((AK) >> (J)) ^ (AKJ)) & (M); \
                             (AK) ^= _t << (J); (AKJ) ^= _t; }
#define UMX(A, B) ((A) > (B) ? (A) : (B))

#define SELSTEP_BL(TB, BITV) { \
    const unsigned eb = E & (TB); \
    int cl = __builtin_popcount(eb); \
    cl += __shfl_xor(cl, 1); \
    cl += __shfl_xor(cl, 2); \
    cl += __shfl_xor(cl, 4); \
    cl += __shfl_xor(cl, 8); \
    cl += __shfl_xor(cl, 16); \
    cl += __shfl_xor(cl, 32); \
    const int cnt = gcnt + cl; \
    const bool up = (cnt >= KK); \
    T = up ? (T | (BITV)) : T; \
    E = up ? eb : (E & ~(TB)); \
    gcnt = up ? gcnt : cnt; \
}

#define MNU(U) { const unsigned _v = (U) >= T ? (U) : 0xffffffffu; mn = _v < mn ? _v : mn; }

#define EXG(UA, UB, UC, UD, OFF) { \
    const float ea = (UA) >= T ? __expf(ord2f(UA) - mx) : 0.f; \
    const float eb_ = (UB) >= T ? __expf(ord2f(UB) - mx) : 0.f; \
    const float ec = (UC) >= T ? __expf(ord2f(UC) - mx) : 0.f; \
    const float ed = (UD) >= T ? __expf(ord2f(UD) - mx) : 0.f; \
    uint4 wv; \
    wv.x = ((unsigned)f2bf(ea)) << 16; \
    wv.y = ((unsigned)f2bf(eb_)) << 16; \
    wv.z = ((unsigned)f2bf(ec)) << 16; \
    wv.w = ((unsigned)f2bf(ed)) << 16; \
    *(uint4*)(R + (OFF) + lane * 4) = wv; \
    lsum += ea + eb_ + ec + ed; }

__device__ __forceinline__ float row_pass(unsigned* R, const int lane)
{
    // ---- load the lane's 32-element slice: 8x ds_read_b128, all named ----
    const uint4 q0 = *(const uint4*)(R + 0 * 256 + lane * 4);
    const uint4 q1 = *(const uint4*)(R + 1 * 256 + lane * 4);
    const uint4 q2 = *(const uint4*)(R + 2 * 256 + lane * 4);
    const uint4 q3 = *(const uint4*)(R + 3 * 256 + lane * 4);
    const uint4 q4 = *(const uint4*)(R + 4 * 256 + lane * 4);
    const uint4 q5 = *(const uint4*)(R + 5 * 256 + lane * 4);
    const uint4 q6 = *(const uint4*)(R + 6 * 256 + lane * 4);
    const uint4 q7 = *(const uint4*)(R + 7 * 256 + lane * 4);
    const unsigned u0  = q0.x, u1  = q0.y, u2  = q0.z, u3  = q0.w;
    const unsigned u4  = q1.x, u5  = q1.y, u6  = q1.z, u7  = q1.w;
    const unsigned u8  = q2.x, u9  = q2.y, u10 = q2.z, u11 = q2.w;
    const unsigned u12 = q3.x, u13 = q3.y, u14 = q3.z, u15 = q3.w;
    const unsigned u16 = q4.x, u17 = q4.y, u18 = q4.z, u19 = q4.w;
    const unsigned u20 = q5.x, u21 = q5.y, u22 = q5.z, u23 = q5.w;
    const unsigned u24 = q6.x, u25 = q6.y, u26 = q6.z, u27 = q6.w;
    const unsigned u28 = q7.x, u29 = q7.y, u30 = q7.z, u31 = q7.w;

    // ---- row max (tree + wave reduce) ----
    const unsigned a0 = UMX(u0, u1),  a1 = UMX(u2, u3),  a2 = UMX(u4, u5),  a3 = UMX(u6, u7);
    const unsigned a4 = UMX(u8, u9),  a5 = UMX(u10, u11), a6 = UMX(u12, u13), a7 = UMX(u14, u15);
    const unsigned a8 = UMX(u16, u17), a9 = UMX(u18, u19), a10 = UMX(u20, u21), a11 = UMX(u22, u23);
    const unsigned a12 = UMX(u24, u25), a13 = UMX(u26, u27), a14 = UMX(u28, u29), a15 = UMX(u30, u31);
    const unsigned b0 = UMX(a0, a1), b1 = UMX(a2, a3), b2 = UMX(a4, a5), b3 = UMX(a6, a7);
    const unsigned b4 = UMX(a8, a9), b5 = UMX(a10, a11), b6 = UMX(a12, a13), b7 = UMX(a14, a15);
    const unsigned c0 = UMX(b0, b1), c1 = UMX(b2, b3), c2 = UMX(b4, b5), c3 = UMX(b6, b7);
    unsigned umx = UMX(UMX(c0, c1), UMX(c2, c3));
#pragma unroll
    for (int off = 32; off >= 1; off >>= 1) {
        const unsigned o = (unsigned)__shfl_xor((int)umx, off);
        umx = o > umx ? o : umx;
    }
    const float mx = ord2f(umx);

    // ---- 32x32 bit transpose: t{b} bit j = bit b of u{j} ----
    unsigned t0 = u0,  t1 = u1,  t2 = u2,  t3 = u3,  t4 = u4,  t5 = u5,  t6 = u6,  t7 = u7;
    unsigned t8 = u8,  t9 = u9,  t10 = u10, t11 = u11, t12 = u12, t13 = u13, t14 = u14, t15 = u15;
    unsigned t16 = u16, t17 = u17, t18 = u18, t19 = u19, t20 = u20, t21 = u21, t22 = u22, t23 = u23;
    unsigned t24 = u24, t25 = u25, t26 = u26, t27 = u27, t28 = u28, t29 = u29, t30 = u30, t31 = u31;
    TRP(t0, t16, 16, 0x0000FFFFu) TRP(t1, t17, 16, 0x0000FFFFu)
    TRP(t2, t18, 16, 0x0000FFFFu) TRP(t3, t19, 16, 0x0000FFFFu)
    TRP(t4, t20, 16, 0x0000FFFFu) TRP(t5, t21, 16, 0x0000FFFFu)
    TRP(t6, t22, 16, 0x0000FFFFu) TRP(t7, t23, 16, 0x0000FFFFu)
    TRP(t8, t24, 16, 0x0000FFFFu) TRP(t9, t25, 16, 0x0000FFFFu)
    TRP(t10, t26, 16, 0x0000FFFFu) TRP(t11, t27, 16, 0x0000FFFFu)
    TRP(t12, t28, 16, 0x0000FFFFu) TRP(t13, t29, 16, 0x0000FFFFu)
    TRP(t14, t30, 16, 0x0000FFFFu) TRP(t15, t31, 16, 0x0000FFFFu)
    TRP(t0, t8, 8, 0x00FF00FFu)  TRP(t1, t9, 8, 0x00FF00FFu)
    TRP(t2, t10, 8, 0x00FF00FFu) TRP(t3, t11, 8, 0x00FF00FFu)
    TRP(t4, t12, 8, 0x00FF00FFu) TRP(t5, t13, 8, 0x00FF00FFu)
    TRP(t6, t14, 8, 0x00FF00FFu) TRP(t7, t15, 8, 0x00FF00FFu)
    TRP(t16, t24, 8, 0x00FF00FFu) TRP(t17, t25, 8, 0x00FF00FFu)
    TRP(t18, t26, 8, 0x00FF00FFu) TRP(t19, t27, 8, 0x00FF00FFu)
    TRP(t20, t28, 8, 0x00FF00FFu) TRP(t21, t29, 8, 0x00FF00FFu)
    TRP(t22, t30, 8, 0x00FF00FFu) TRP(t23, t31, 8, 0x00FF00FFu)
    TRP(t0, t4, 4, 0x0F0F0F0Fu)  TRP(t1, t5, 4, 0x0F0F0F0Fu)
    TRP(t2, t6, 4, 0x0F0F0F0Fu)  TRP(t3, t7, 4, 0x0F0F0F0Fu)
    TRP(t8, t12, 4, 0x0F0F0F0Fu) TRP(t9, t13, 4, 0x0F0F0F0Fu)
    TRP(t10, t14, 4, 0x0F0F0F0Fu) TRP(t11, t15, 4, 0x0F0F0F0Fu)
    TRP(t16, t20, 4, 0x0F0F0F0Fu) TRP(t17, t21, 4, 0x0F0F0F0Fu)
    TRP(t18, t22, 4, 0x0F0F0F0Fu) TRP(t19, t23, 4, 0x0F0F0F0Fu)
    TRP(t24, t28, 4, 0x0F0F0F0Fu) TRP(t25, t29, 4, 0x0F0F0F0Fu)
    TRP(t26, t30, 4, 0x0F0F0F0Fu) TRP(t27, t31, 4, 0x0F0F0F0Fu)
    TRP(t0, t2, 2, 0x33333333u)  TRP(t1, t3, 2, 0x33333333u)
    TRP(t4, t6, 2, 0x33333333u)  TRP(t5, t7, 2, 0x33333333u)
    TRP(t8, t10, 2, 0x33333333u) TRP(t9, t11, 2, 0x33333333u)
    TRP(t12, t14, 2, 0x33333333u) TRP(t13, t15, 2, 0x33333333u)
    TRP(t16, t18, 2, 0x33333333u) TRP(t17, t19, 2, 0x33333333u)
    TRP(t20, t22, 2, 0x33333333u) TRP(t21, t23, 2, 0x33333333u)
    TRP(t24, t26, 2, 0x33333333u) TRP(t25, t27, 2, 0x33333333u)
    TRP(t28, t30, 2, 0x33333333u) TRP(t29, t31, 2, 0x33333333u)
    TRP(t0, t1, 1, 0x55555555u)  TRP(t2, t3, 1, 0x55555555u)
    TRP(t4, t5, 1, 0x55555555u)  TRP(t6, t7, 1, 0x55555555u)
    TRP(t8, t9, 1, 0x55555555u)  TRP(t10, t11, 1, 0x55555555u)
    TRP(t12, t13, 1, 0x55555555u) TRP(t14, t15, 1, 0x55555555u)
    TRP(t16, t17, 1, 0x55555555u) TRP(t18, t19, 1, 0x55555555u)
    TRP(t20, t21, 1, 0x55555555u) TRP(t22, t23, 1, 0x55555555u)
    TRP(t24, t25, 1, 0x55555555u) TRP(t26, t27, 1, 0x55555555u)
    TRP(t28, t29, 1, 0x55555555u) TRP(t30, t31, 1, 0x55555555u)

    // ---- branchless rank-count binary search over bit-planes ----
    unsigned T = 0u, E = 0xffffffffu;
    int gcnt = 0;
    SELSTEP_BL(t31, 1u << 31) SELSTEP_BL(t30, 1u << 30) SELSTEP_BL(t29, 1u << 29) SELSTEP_BL(t28, 1u << 28)
    SELSTEP_BL(t27, 1u << 27) SELSTEP_BL(t26, 1u << 26) SELSTEP_BL(t25, 1u << 25) SELSTEP_BL(t24, 1u << 24)
    SELSTEP_BL(t23, 1u << 23) SELSTEP_BL(t22, 1u << 22) SELSTEP_BL(t21, 1u << 21) SELSTEP_BL(t20, 1u << 20)
    SELSTEP_BL(t19, 1u << 19) SELSTEP_BL(t18, 1u << 18) SELSTEP_BL(t17, 1u << 17) SELSTEP_BL(t16, 1u << 16)
    SELSTEP_BL(t15, 1u << 15) SELSTEP_BL(t14, 1u << 14) SELSTEP_BL(t13, 1u << 13) SELSTEP_BL(t12, 1u << 12)
    SELSTEP_BL(t11, 1u << 11) SELSTEP_BL(t10, 1u << 10) SELSTEP_BL(t9, 1u << 9)   SELSTEP_BL(t8, 1u << 8)
    SELSTEP_BL(t7, 1u << 7)   SELSTEP_BL(t6, 1u << 6)   SELSTEP_BL(t5, 1u << 5)   SELSTEP_BL(t4, 1u << 4)
    SELSTEP_BL(t3, 1u << 3)   SELSTEP_BL(t2, 1u << 2)   SELSTEP_BL(t1, 1u << 1)   SELSTEP_BL(t0, 1u)

    // threshold = min{u >= T} (== T; kept as cheap tie-exact insurance)
    {
        unsigned mn = 0xffffffffu;
        MNU(u0) MNU(u1) MNU(u2) MNU(u3) MNU(u4) MNU(u5) MNU(u6) MNU(u7)
        MNU(u8) MNU(u9) MNU(u10) MNU(u11) MNU(u12) MNU(u13) MNU(u14) MNU(u15)
        MNU(u16) MNU(u17) MNU(u18) MNU(u19) MNU(u20) MNU(u21) MNU(u22) MNU(u23)
        MNU(u24) MNU(u25) MNU(u26) MNU(u27) MNU(u28) MNU(u29) MNU(u30) MNU(u31)
#pragma unroll
        for (int off = 32; off >= 1; off >>= 1) {
            const unsigned o = (unsigned)__shfl_xor((int)mn, off);
            mn = o < mn ? o : mn;
        }
        T = mn;
    }

    // ---- softmax numerators; bf16 P in-place into hi-16 of score words ----
    float lsum = 0.f;
    EXG(u0, u1, u2, u3, 0 * 256)    EXG(u4, u5, u6, u7, 1 * 256)
    EXG(u8, u9, u10, u11, 2 * 256)  EXG(u12, u13, u14, u15, 3 * 256)
    EXG(u16, u17, u18, u19, 4 * 256) EXG(u20, u21, u22, u23, 5 * 256)
    EXG(u24, u25, u26, u27, 6 * 256) EXG(u28, u29, u30, u31, 7 * 256)
#pragma unroll
    for (int off = 32; off >= 1; off >>= 1) lsum += __shfl_xor(lsum, off);
    return 1.f / lsum;
}

// ---------------------------------------------------------------------------
// Fused attention R16 — R13 geometry (16 waves, 1 block/CU), branchless
// SALU-free select.  Single variable vs R13's 565us.
// ---------------------------------------------------------------------------
__global__ __launch_bounds__(1024, 4)
void attn_kernel(const unsigned short* __restrict__ Qh, const unsigned short* __restrict__ Ql,
                 const unsigned short* __restrict__ Kh, const unsigned short* __restrict__ Kl,
                 const unsigned short* __restrict__ Vt,
                 unsigned short* __restrict__ AOh, unsigned short* __restrict__ AOl)
{
    extern __shared__ __align__(16) char smem[];
    unsigned* S = (unsigned*)smem;          // [16][SSTR] ord scores / bf16-P overlay
    float* Opart = (float*)smem;            // overlay [16][16][64] after PV reads done

    const int tid  = threadIdx.x;
    const int lane = tid & 63;
    const int w    = tid >> 6;              // 0..15
    const int q15  = lane & 15;
    const int quad = lane >> 4;

    // XCD swizzle: 4 heads per XCD -> K+V working set ~3 MB, fits 4 MB L2
    const int blk = blockIdx.x;
    const int bh  = (blk & 7) * 4 + ((blk >> 3) & 3);
    const int q0  = (blk >> 5) * 16;

    // ---- Q B-frags direct from global ----
    const size_t qrow = ((size_t)bh * S_LEN + q0 + q15) * HDIM;
    const bf16x8 bqh0 = *(const bf16x8*)(Qh + qrow + quad * 8);
    const bf16x8 bqh1 = *(const bf16x8*)(Qh + qrow + 32 + quad * 8);
    const bf16x8 bql0 = *(const bf16x8*)(Ql + qrow + quad * 8);
    const bf16x8 bql1 = *(const bf16x8*)(Ql + qrow + 32 + quad * 8);

    const size_t kbase = (size_t)bh * S_LEN * HDIM;

    // ---- phase 1: QK^T, 8 key-tiles per wave, straight to LDS ----
#pragma unroll 4
    for (int t = 0; t < 8; ++t) {
        const int key = w * 128 + t * 16 + q15;     // A-frag m
        const unsigned short* kh = Kh + kbase + (size_t)key * HDIM + quad * 8;
        const unsigned short* kl = Kl + kbase + (size_t)key * HDIM + quad * 8;
        const bf16x8 akh0 = *(const bf16x8*)(kh);
        const bf16x8 akh1 = *(const bf16x8*)(kh + 32);
        const bf16x8 akl0 = *(const bf16x8*)(kl);
        const bf16x8 akl1 = *(const bf16x8*)(kl + 32);
        f32x4 c = {0.f, 0.f, 0.f, 0.f};
        c = __builtin_amdgcn_mfma_f32_16x16x32_bf16(akh0, bqh0, c, 0, 0, 0);
        c = __builtin_amdgcn_mfma_f32_16x16x32_bf16(akh1, bqh1, c, 0, 0, 0);
        c = __builtin_amdgcn_mfma_f32_16x16x32_bf16(akh0, bql0, c, 0, 0, 0);
        c = __builtin_amdgcn_mfma_f32_16x16x32_bf16(akh1, bql1, c, 0, 0, 0);
        c = __builtin_amdgcn_mfma_f32_16x16x32_bf16(akl0, bqh0, c, 0, 0, 0);
        c = __builtin_amdgcn_mfma_f32_16x16x32_bf16(akl1, bqh1, c, 0, 0, 0);
        c = c * 0.125f;
        // C-layout: col=lane&15=q(row of S), row-in-tile=quad*4+reg=key(col)
        uint4 o;
        o.x = f2ord(c[0]); o.y = f2ord(c[1]); o.z = f2ord(c[2]); o.w = f2ord(c[3]);
        *(uint4*)(S + q15 * SSTR + w * 128 + t * 16 + quad * 4) = o;
    }
    __syncthreads();   // full [16][2048] score matrix visible

    // ---- phase 2: one row per wave: select + softmax, in-place bf16 P ----
    const float invd = row_pass(S + w * SSTR, lane);
    __syncthreads();   // all P visible

    // ---- phase 3: dense PV via bf16 MFMA, wave w keys [128w,128w+128) ----
    {
        f32x4 oacc[4];
#pragma unroll
        for (int ht = 0; ht < 4; ++ht) oacc[ht] = (f32x4){0.f, 0.f, 0.f, 0.f};
        const size_t vtb = (size_t)bh * HDIM * S_LEN;
        const unsigned* Srow = S + q15 * SSTR;
#pragma unroll 2
        for (int ks = 0; ks < 4; ++ks) {
            const int key0 = w * 128 + ks * 32 + quad * 8;
            const uint4 a0 = *(const uint4*)(Srow + key0);
            const uint4 a1 = *(const uint4*)(Srow + key0 + 4);
            const bf16x8 ap = pack_hi8(a0, a1);                      // A[m=q][k=key]
#pragma unroll
            for (int ht = 0; ht < 4; ++ht) {
                const int hd = ht * 16 + q15;                        // B[k=key][n=hd]
                const bf16x8 bv = *(const bf16x8*)(Vt + vtb + (size_t)hd * S_LEN + key0);
                oacc[ht] = __builtin_amdgcn_mfma_f32_16x16x32_bf16(ap, bv, oacc[ht], 0, 0, 0);
            }
        }
        __syncthreads();   // all P reads done; score region dead -> Opart live
        // D[m=q][n=hd]: col=lane&15=hd-in-tile, row=quad*4+reg=q
#pragma unroll
        for (int ht = 0; ht < 4; ++ht)
#pragma unroll
            for (int rg = 0; rg < 4; ++rg)
                Opart[w * 1024 + (quad * 4 + rg) * 64 + ht * 16 + q15] = oacc[ht][rg];
    }
    __syncthreads();

    // ---- final: wave w reduces 16 partials for row w, writes AO hi/lo ----
    {
        float s = 0.f;
#pragma unroll
        for (int ww = 0; ww < 16; ++ww)
            s += Opart[ww * 1024 + w * 64 + lane];
        const int b = bh >> 4, h = bh & 15;
        const float o = s * invd;
        const size_t i = ((size_t)(b * S_LEN + q0 + w)) * DMODEL + h * HDIM + lane;
        const unsigned short oh = f2bf(o);
        AOh[i] = oh; AOl[i] = f2bf(o - bf2f(oh));
    }
}

// ---------------------------------------------------------------------------
extern "C" void kernel_launch(void* const* d_in, const int* in_sizes, int n_in,
                              void* d_out, int out_size, void* d_ws, size_t ws_size,
                              hipStream_t stream)
{
    const float* X  = (const float*)d_in[0];
    const float* Wq = (const float*)d_in[1];
    const float* bq = (const float*)d_in[2];
    const float* Wk = (const float*)d_in[3];
    const float* bk = (const float*)d_in[4];
    const float* Wv = (const float*)d_in[5];
    const float* bv = (const float*)d_in[6];
    const float* Wo = (const float*)d_in[7];
    const float* bo = (const float*)d_in[8];

    char* p = (char*)d_ws;
    const size_t NEL = (size_t)BHC * S_LEN * HDIM;   // 4,194,304
    unsigned short* Q16h = (unsigned short*)p; p += NEL * 2;
    unsigned short* Q16l = (unsigned short*)p; p += NEL * 2;
    unsigned short* K16h = (unsigned short*)p; p += NEL * 2;
    unsigned short* K16l = (unsigned short*)p; p += NEL * 2;
    unsigned short* Vb16 = (unsigned short*)p; p += NEL * 2;
    unsigned short* Vt16 = (unsigned short*)p; p += NEL * 2;
    unsigned short* Xh   = (unsigned short*)p; p += NEL * 2;
    unsigned short* Xl   = (unsigned short*)p; p += NEL * 2;
    unsigned short* AOh  = (unsigned short*)p; p += NEL * 2;
    unsigned short* AOl  = (unsigned short*)p; p += NEL * 2;
    unsigned short* Wqh  = (unsigned short*)p; p += DMODEL * DMODEL * 2;
    unsigned short* Wql  = (unsigned short*)p; p += DMODEL * DMODEL * 2;
    unsigned short* Wkh  = (unsigned short*)p; p += DMODEL * DMODEL * 2;
    unsigned short* Wkl  = (unsigned short*)p; p += DMODEL * DMODEL * 2;
    unsigned short* Wvh  = (unsigned short*)p; p += DMODEL * DMODEL * 2;
    unsigned short* Wvl  = (unsigned short*)p; p += DMODEL * DMODEL * 2;
    unsigned short* Woh  = (unsigned short*)p; p += DMODEL * DMODEL * 2;
    unsigned short* Wol  = (unsigned short*)p; p += DMODEL * DMODEL * 2;

    const int attn_lds = 16 * SSTR * 4;   // 131,328 B -> 1 block/CU
    hipFuncSetAttribute((const void*)attn_kernel,
                        hipFuncAttributeMaxDynamicSharedMemorySize, attn_lds);

    const int X4 = (int)(NEL / 4);
    const int W4 = DMODEL * DMODEL / 4;

    // ---- input splits ----
    split32<<<(X4 + 255) / 256, 256, 0, stream>>>(X,  Xh,  Xl,  X4);
    split32<<<(W4 + 255) / 256, 256, 0, stream>>>(Wq, Wqh, Wql, W4);
    split32<<<(W4 + 255) / 256, 256, 0, stream>>>(Wk, Wkh, Wkl, W4);
    split32<<<(W4 + 255) / 256, 256, 0, stream>>>(Wv, Wvh, Wvl, W4);
    split32<<<(W4 + 255) / 256, 256, 0, stream>>>(Wo, Woh, Wol, W4);

    // ---- projections ----
    const dim3 ggrid(16, 32, 1);
    gemm_mfma<<<ggrid, 256, 0, stream>>>(Xh, Xl, Wqh, Wql, bq, Q16h, Q16l, 2);
    gemm_mfma<<<ggrid, 256, 0, stream>>>(Xh, Xl, Wkh, Wkl, bk, K16h, K16l, 2);
    gemm_mfma<<<ggrid, 256, 0, stream>>>(Xh, Xl, Wvh, Wvl, bv, Vb16, nullptr, 3);
    transpose_v16<<<dim3(32, 32, 1), 256, 0, stream>>>(Vb16, Vt16);

    // ---- fused attention (R16: branchless SALU-free select) ----
    attn_kernel<<<4096, 1024, attn_lds, stream>>>(Q16h, Q16l, K16h, K16l, Vt16, AOh, AOl);

    // ---- output projection ----
    gemm_mfma<<<ggrid, 256, 0, stream>>>(AOh, AOl, Woh, Wol, bo, d_out, nullptr, 0);
}

// Round 11
// 804.310 us; speedup vs baseline: 2.1543x; 1.0397x over previous
//
#include <hip/hip_runtime.h>
#include <math.h>

#define S_LEN 2048
#define NH 16
#define HDIM 64
#define BATCH 2
#define BHC 32          // BATCH*NH
#define KK 409          // int(2048 * (1.0 - 0.8)) per reference float math
#define DMODEL 1024

typedef __attribute__((ext_vector_type(8))) short bf16x8;   // 8 bf16 in 4 VGPRs
typedef __attribute__((ext_vector_type(4))) float f32x4;

// LDS-resident score matrix. 16 rows * 2052 * 4 B = 131,328 B -> 1 block/CU.
// 2052 % 32 == 4 -> no hot bank on any access pattern below.
#define SSTR 2052
#define T_STR  40       // bf16 LDS tile row stride for gemm: 80 B, 16B-aligned

__device__ __forceinline__ unsigned f2ord(float f) {
    unsigned u = __float_as_uint(f);
    return (u & 0x80000000u) ? ~u : (u | 0x80000000u);
}
__device__ __forceinline__ float ord2f(unsigned v) {
    unsigned u = (v & 0x80000000u) ? (v & 0x7fffffffu) : ~v;
    return __uint_as_float(u);
}
__device__ __forceinline__ unsigned short f2bf(float f) {   // RNE
    unsigned u = __float_as_uint(f);
    u += 0x7fffu + ((u >> 16) & 1u);
    return (unsigned short)(u >> 16);
}
__device__ __forceinline__ float bf2f(unsigned short h) {
    return __uint_as_float(((unsigned)h) << 16);
}

// ---------------------------------------------------------------------------
// fp32 -> bf16 hi/lo split (vectorized float4 / ushort4), n4 = elements/4
// ---------------------------------------------------------------------------
__global__ __launch_bounds__(256)
void split32(const float* __restrict__ in, unsigned short* __restrict__ hi,
             unsigned short* __restrict__ lo, int n4)
{
    const int i = blockIdx.x * 256 + threadIdx.x;
    if (i < n4) {
        const float4 v = ((const float4*)in)[i];
        ushort4 h, l;
        h.x = f2bf(v.x); l.x = f2bf(v.x - bf2f(h.x));
        h.y = f2bf(v.y); l.y = f2bf(v.y - bf2f(h.y));
        h.z = f2bf(v.z); l.z = f2bf(v.z - bf2f(h.z));
        h.w = f2bf(v.w); l.w = f2bf(v.w - bf2f(h.w));
        ((ushort4*)hi)[i] = h;
        ((ushort4*)lo)[i] = l;
    }
}

// ---------------------------------------------------------------------------
// LDS-staged split-bf16 3-pass MFMA GEMM (unchanged — R8 banked structure).
// ---------------------------------------------------------------------------
__global__ __launch_bounds__(256)
void gemm_mfma(const unsigned short* __restrict__ Ah, const unsigned short* __restrict__ Al,
               const unsigned short* __restrict__ Bh, const unsigned short* __restrict__ Bl,
               const float* __restrict__ bias, void* __restrict__ out0,
               void* __restrict__ out1, int mode)
{
    __shared__ __align__(16) unsigned short sAh[128 * T_STR];
    __shared__ __align__(16) unsigned short sAl[128 * T_STR];
    __shared__ __align__(16) unsigned short sBh[64 * T_STR];
    __shared__ __align__(16) unsigned short sBl[64 * T_STR];

    const int tid  = threadIdx.x;
    const int lane = tid & 63;
    const int w    = tid >> 6;
    const int q15  = lane & 15;
    const int quad = lane >> 4;
    const int n0b = blockIdx.x * 64;
    const int m0b = blockIdx.y * 128;
    const int wm = (w >> 1) * 64;
    const int wn = (w & 1) * 32;

    const int ar0 = tid >> 2, aks0 = (tid & 3) * 8;
    const int ar1 = (tid + 256) >> 2, aks1 = aks0;
    const int br = tid >> 2, bks = (tid & 3) * 8;

    const unsigned short* gAh0 = Ah + (size_t)(m0b + ar0) * 1024 + aks0;
    const unsigned short* gAh1 = Ah + (size_t)(m0b + ar1) * 1024 + aks1;
    const unsigned short* gAl0 = Al + (size_t)(m0b + ar0) * 1024 + aks0;
    const unsigned short* gAl1 = Al + (size_t)(m0b + ar1) * 1024 + aks1;
    const unsigned short* gBh = Bh + (size_t)(n0b + br) * 1024 + bks;
    const unsigned short* gBl = Bl + (size_t)(n0b + br) * 1024 + bks;

    f32x4 acc[4][2];
#pragma unroll
    for (int mt = 0; mt < 4; ++mt)
#pragma unroll
        for (int nt = 0; nt < 2; ++nt) acc[mt][nt] = (f32x4){0.f, 0.f, 0.f, 0.f};

#pragma unroll 1
    for (int k0 = 0; k0 < 1024; k0 += 32) {
        const bf16x8 vah0 = *(const bf16x8*)(gAh0 + k0);
        const bf16x8 vah1 = *(const bf16x8*)(gAh1 + k0);
        const bf16x8 val0 = *(const bf16x8*)(gAl0 + k0);
        const bf16x8 val1 = *(const bf16x8*)(gAl1 + k0);
        const bf16x8 vbh  = *(const bf16x8*)(gBh + k0);
        const bf16x8 vbl  = *(const bf16x8*)(gBl + k0);
        __syncthreads();
        *(bf16x8*)(sAh + ar0 * T_STR + aks0) = vah0;
        *(bf16x8*)(sAh + ar1 * T_STR + aks1) = vah1;
        *(bf16x8*)(sAl + ar0 * T_STR + aks0) = val0;
        *(bf16x8*)(sAl + ar1 * T_STR + aks1) = val1;
        *(bf16x8*)(sBh + br * T_STR + bks) = vbh;
        *(bf16x8*)(sBl + br * T_STR + bks) = vbl;
        __syncthreads();

        bf16x8 fbh[2], fbl[2];
#pragma unroll
        for (int nt = 0; nt < 2; ++nt) {
            fbh[nt] = *(const bf16x8*)(sBh + (wn + nt * 16 + q15) * T_STR + quad * 8);
            fbl[nt] = *(const bf16x8*)(sBl + (wn + nt * 16 + q15) * T_STR + quad * 8);
        }
#pragma unroll
        for (int mt = 0; mt < 4; ++mt) {
            const bf16x8 fah = *(const bf16x8*)(sAh + (wm + mt * 16 + q15) * T_STR + quad * 8);
            const bf16x8 fal = *(const bf16x8*)(sAl + (wm + mt * 16 + q15) * T_STR + quad * 8);
#pragma unroll
            for (int nt = 0; nt < 2; ++nt) {
                acc[mt][nt] = __builtin_amdgcn_mfma_f32_16x16x32_bf16(fah, fbh[nt], acc[mt][nt], 0, 0, 0);
                acc[mt][nt] = __builtin_amdgcn_mfma_f32_16x16x32_bf16(fah, fbl[nt], acc[mt][nt], 0, 0, 0);
                acc[mt][nt] = __builtin_amdgcn_mfma_f32_16x16x32_bf16(fal, fbh[nt], acc[mt][nt], 0, 0, 0);
            }
        }
    }

#pragma unroll
    for (int nt = 0; nt < 2; ++nt) {
        const int n = n0b + wn + nt * 16 + q15;
        const float bv = bias[n];
#pragma unroll
        for (int mt = 0; mt < 4; ++mt) {
            const int mb = m0b + wm + mt * 16 + quad * 4;
#pragma unroll
            for (int rg = 0; rg < 4; ++rg) {
                const int m = mb + rg;
                const float o = acc[mt][nt][rg] + bv;
                if (mode == 0) {
                    ((float*)out0)[(size_t)m * 1024 + n] = o;
                } else {
                    const int b = m >> 11, s = m & 2047;
                    const int h = n >> 6, hd = n & 63;
                    const size_t base = ((size_t)((b * NH + h) * S_LEN + s)) * HDIM + hd;
                    if (mode == 3) {
                        ((unsigned short*)out0)[base] = f2bf(o);
                    } else {
                        const unsigned short oh = f2bf(o);
                        ((unsigned short*)out0)[base] = oh;
                        ((unsigned short*)out1)[base] = f2bf(o - bf2f(oh));
                    }
                }
            }
        }
    }
}

// ---------------------------------------------------------------------------
// V bf16 [bh][s][64] -> Vt bf16 [bh][64][2048]
// ---------------------------------------------------------------------------
__global__ __launch_bounds__(256)
void transpose_v16(const unsigned short* __restrict__ V, unsigned short* __restrict__ Vt)
{
    __shared__ unsigned short t[64][72];
    const int tid = threadIdx.x;
    const int s0 = blockIdx.x * 64;
    const int bh = blockIdx.y;
    const unsigned short* Vb = V + (size_t)bh * S_LEN * HDIM;
#pragma unroll
    for (int i = 0; i < 4; ++i) {
        const int f = tid + i * 256;
        const int s = f >> 4;
        const int hq = (f & 15) * 4;
        const ushort4 v = *(const ushort4*)(Vb + (size_t)(s0 + s) * HDIM + hq);
        t[s][hq + 0] = v.x; t[s][hq + 1] = v.y; t[s][hq + 2] = v.z; t[s][hq + 3] = v.w;
    }
    __syncthreads();
    unsigned short* Vtb = Vt + (size_t)bh * HDIM * S_LEN;
#pragma unroll
    for (int i = 0; i < 4; ++i) {
        const int f = tid + i * 256;
        const int hd = f >> 4;
        const int sq = (f & 15) * 4;
        ushort4 v;
        v.x = t[sq + 0][hd]; v.y = t[sq + 1][hd];
        v.z = t[sq + 2][hd]; v.w = t[sq + 3][hd];
        *(ushort4*)(Vtb + (size_t)hd * S_LEN + s0 + sq) = v;
    }
}

__device__ __forceinline__ bf16x8 pack_hi8(const uint4 a0, const uint4 a1)
{
    union { unsigned u[4]; bf16x8 v; } c;
    c.u[0] = (a0.x >> 16) | (a0.y & 0xffff0000u);
    c.u[1] = (a0.z >> 16) | (a0.w & 0xffff0000u);
    c.u[2] = (a1.x >> 16) | (a1.y & 0xffff0000u);
    c.u[3] = (a1.z >> 16) | (a1.w & 0xffff0000u);
    return c.v;
}

// ---------------------------------------------------------------------------
// R17 phase-2 row pass — 2-BIT radix steps (16 steps, half the chain).
// (R16 post-mortem: SALU-throughput theory dead — zero-SALU select was
//  SLOWER because 6-deep shfl chains out-latency ballots.  Remaining theory:
//  select is bound by the 32-step serial chain (~150-250cyc/step VALU->
//  ballot->SALU->branch round trip).  Examining 2 bits/step halves the
//  chain; the 18 ballots per step are mutually independent (parallel), so
//  step latency stays ~flat while step count halves.)
//
// Invariant (generalized from the proven 1-bit rank-count select):
//  before a pair: gcnt = #elems with higher-bits > T's; E marks elems whose
//  higher bits == T's.  Per pair (b1,b0): n3/n2/n1 = wave counts of E-elems
//  with pair bits 11/10/01.  Cascade cnt3=gcnt+n3, cnt2=cnt3+n2,
//  cnt1=cnt2+n1; choose the largest prefix with cnt>=KK; update E,gcnt.
//  Early exit on cnt==KK; final threshold = min{u >= T} (tie-exact, same
//  as R8..R13/R16-verified tail).
// ---------------------------------------------------------------------------
#define TRP(AK, AKJ, J, M) { const unsigned _t = (((AK) >> (J)) ^ (AKJ)) & (M); \
                             (AK) ^= _t << (J); (AKJ) ^= _t; }
#define UMX(A, B) ((A) > (B) ? (A) : (B))

#define WSUM6(N, C) { \
    N  = (int)__builtin_popcountll(__ballot((C) & 1)); \
    N += (int)__builtin_popcountll(__ballot((C) & 2)) << 1; \
    N += (int)__builtin_popcountll(__ballot((C) & 4)) << 2; \
    N += (int)__builtin_popcountll(__ballot((C) & 8)) << 3; \
    N += (int)__builtin_popcountll(__ballot((C) & 16)) << 4; \
    N += (int)__builtin_popcountll(__ballot((C) & 32)) << 5; \
}

#define SEL2(TB1, TB0, B1V, B0V) { \
    const unsigned m3 = (TB1) & (TB0); \
    const unsigned m2 = (TB1) & ~(TB0); \
    const unsigned m1 = (~(TB1)) & (TB0); \
    const int c3 = __builtin_popcount(E & m3); \
    const int c2 = __builtin_popcount(E & m2); \
    const int c1 = __builtin_popcount(E & m1); \
    int n3, n2, n1; \
    WSUM6(n3, c3) WSUM6(n2, c2) WSUM6(n1, c1) \
    const int cnt3 = gcnt + n3; \
    if (cnt3 >= KK) { \
        T |= (B1V) | (B0V); E &= m3; \
        if (cnt3 == KK) goto sel_done; \
    } else { \
        const int cnt2 = cnt3 + n2; \
        if (cnt2 >= KK) { \
            T |= (B1V); E &= m2; gcnt = cnt3; \
            if (cnt2 == KK) goto sel_done; \
        } else { \
            const int cnt1 = cnt2 + n1; \
            if (cnt1 >= KK) { \
                T |= (B0V); E &= m1; gcnt = cnt2; \
                if (cnt1 == KK) goto sel_done; \
            } else { \
                E &= ~((TB1) | (TB0)); gcnt = cnt1; \
            } \
        } \
    } \
}

#define MNU(U) { const unsigned _v = (U) >= T ? (U) : 0xffffffffu; mn = _v < mn ? _v : mn; }

#define EXG(UA, UB, UC, UD, OFF) { \
    const float ea = (UA) >= T ? __expf(ord2f(UA) - mx) : 0.f; \
    const float eb_ = (UB) >= T ? __expf(ord2f(UB) - mx) : 0.f; \
    const float ec = (UC) >= T ? __expf(ord2f(UC) - mx) : 0.f; \
    const float ed = (UD) >= T ? __expf(ord2f(UD) - mx) : 0.f; \
    uint4 wv; \
    wv.x = ((unsigned)f2bf(ea)) << 16; \
    wv.y = ((unsigned)f2bf(eb_)) << 16; \
    wv.z = ((unsigned)f2bf(ec)) << 16; \
    wv.w = ((unsigned)f2bf(ed)) << 16; \
    *(uint4*)(R + (OFF) + lane * 4) = wv; \
    lsum += ea + eb_ + ec + ed; }

__device__ __forceinline__ float row_pass(unsigned* R, const int lane)
{
    // ---- load the lane's 32-element slice: 8x ds_read_b128, all named ----
    const uint4 q0 = *(const uint4*)(R + 0 * 256 + lane * 4);
    const uint4 q1 = *(const uint4*)(R + 1 * 256 + lane * 4);
    const uint4 q2 = *(const uint4*)(R + 2 * 256 + lane * 4);
    const uint4 q3 = *(const uint4*)(R + 3 * 256 + lane * 4);
    const uint4 q4 = *(const uint4*)(R + 4 * 256 + lane * 4);
    const uint4 q5 = *(const uint4*)(R + 5 * 256 + lane * 4);
    const uint4 q6 = *(const uint4*)(R + 6 * 256 + lane * 4);
    const uint4 q7 = *(const uint4*)(R + 7 * 256 + lane * 4);
    const unsigned u0  = q0.x, u1  = q0.y, u2  = q0.z, u3  = q0.w;
    const unsigned u4  = q1.x, u5  = q1.y, u6  = q1.z, u7  = q1.w;
    const unsigned u8  = q2.x, u9  = q2.y, u10 = q2.z, u11 = q2.w;
    const unsigned u12 = q3.x, u13 = q3.y, u14 = q3.z, u15 = q3.w;
    const unsigned u16 = q4.x, u17 = q4.y, u18 = q4.z, u19 = q4.w;
    const unsigned u20 = q5.x, u21 = q5.y, u22 = q5.z, u23 = q5.w;
    const unsigned u24 = q6.x, u25 = q6.y, u26 = q6.z, u27 = q6.w;
    const unsigned u28 = q7.x, u29 = q7.y, u30 = q7.z, u31 = q7.w;

    // ---- row max (tree + wave reduce) ----
    const unsigned a0 = UMX(u0, u1),  a1 = UMX(u2, u3),  a2 = UMX(u4, u5),  a3 = UMX(u6, u7);
    const unsigned a4 = UMX(u8, u9),  a5 = UMX(u10, u11), a6 = UMX(u12, u13), a7 = UMX(u14, u15);
    const unsigned a8 = UMX(u16, u17), a9 = UMX(u18, u19), a10 = UMX(u20, u21), a11 = UMX(u22, u23);
    const unsigned a12 = UMX(u24, u25), a13 = UMX(u26, u27), a14 = UMX(u28, u29), a15 = UMX(u30, u31);
    const unsigned b0 = UMX(a0, a1), b1 = UMX(a2, a3), b2 = UMX(a4, a5), b3 = UMX(a6, a7);
    const unsigned b4 = UMX(a8, a9), b5 = UMX(a10, a11), b6 = UMX(a12, a13), b7 = UMX(a14, a15);
    const unsigned c0 = UMX(b0, b1), c1 = UMX(b2, b3), c2 = UMX(b4, b5), c3 = UMX(b6, b7);
    unsigned umx = UMX(UMX(c0, c1), UMX(c2, c3));
#pragma unroll
    for (int off = 32; off >= 1; off >>= 1) {
        const unsigned o = (unsigned)__shfl_xor((int)umx, off);
        umx = o > umx ? o : umx;
    }
    const float mx = ord2f(umx);

    // ---- 32x32 bit transpose: t{b} bit j = bit b of u{j} ----
    unsigned t0 = u0,  t1 = u1,  t2 = u2,  t3 = u3,  t4 = u4,  t5 = u5,  t6 = u6,  t7 = u7;
    unsigned t8 = u8,  t9 = u9,  t10 = u10, t11 = u11, t12 = u12, t13 = u13, t14 = u14, t15 = u15;
    unsigned t16 = u16, t17 = u17, t18 = u18, t19 = u19, t20 = u20, t21 = u21, t22 = u22, t23 = u23;
    unsigned t24 = u24, t25 = u25, t26 = u26, t27 = u27, t28 = u28, t29 = u29, t30 = u30, t31 = u31;
    TRP(t0, t16, 16, 0x0000FFFFu) TRP(t1, t17, 16, 0x0000FFFFu)
    TRP(t2, t18, 16, 0x0000FFFFu) TRP(t3, t19, 16, 0x0000FFFFu)
    TRP(t4, t20, 16, 0x0000FFFFu) TRP(t5, t21, 16, 0x0000FFFFu)
    TRP(t6, t22, 16, 0x0000FFFFu) TRP(t7, t23, 16, 0x0000FFFFu)
    TRP(t8, t24, 16, 0x0000FFFFu) TRP(t9, t25, 16, 0x0000FFFFu)
    TRP(t10, t26, 16, 0x0000FFFFu) TRP(t11, t27, 16, 0x0000FFFFu)
    TRP(t12, t28, 16, 0x0000FFFFu) TRP(t13, t29, 16, 0x0000FFFFu)
    TRP(t14, t30, 16, 0x0000FFFFu) TRP(t15, t31, 16, 0x0000FFFFu)
    TRP(t0, t8, 8, 0x00FF00FFu)  TRP(t1, t9, 8, 0x00FF00FFu)
    TRP(t2, t10, 8, 0x00FF00FFu) TRP(t3, t11, 8, 0x00FF00FFu)
    TRP(t4, t12, 8, 0x00FF00FFu) TRP(t5, t13, 8, 0x00FF00FFu)
    TRP(t6, t14, 8, 0x00FF00FFu) TRP(t7, t15, 8, 0x00FF00FFu)
    TRP(t16, t24, 8, 0x00FF00FFu) TRP(t17, t25, 8, 0x00FF00FFu)
    TRP(t18, t26, 8, 0x00FF00FFu) TRP(t19, t27, 8, 0x00FF00FFu)
    TRP(t20, t28, 8, 0x00FF00FFu) TRP(t21, t29, 8, 0x00FF00FFu)
    TRP(t22, t30, 8, 0x00FF00FFu) TRP(t23, t31, 8, 0x00FF00FFu)
    TRP(t0, t4, 4, 0x0F0F0F0Fu)  TRP(t1, t5, 4, 0x0F0F0F0Fu)
    TRP(t2, t6, 4, 0x0F0F0F0Fu)  TRP(t3, t7, 4, 0x0F0F0F0Fu)
    TRP(t8, t12, 4, 0x0F0F0F0Fu) TRP(t9, t13, 4, 0x0F0F0F0Fu)
    TRP(t10, t14, 4, 0x0F0F0F0Fu) TRP(t11, t15, 4, 0x0F0F0F0Fu)
    TRP(t16, t20, 4, 0x0F0F0F0Fu) TRP(t17, t21, 4, 0x0F0F0F0Fu)
    TRP(t18, t22, 4, 0x0F0F0F0Fu) TRP(t19, t23, 4, 0x0F0F0F0Fu)
    TRP(t24, t28, 4, 0x0F0F0F0Fu) TRP(t25, t29, 4, 0x0F0F0F0Fu)
    TRP(t26, t30, 4, 0x0F0F0F0Fu) TRP(t27, t31, 4, 0x0F0F0F0Fu)
    TRP(t0, t2, 2, 0x33333333u)  TRP(t1, t3, 2, 0x33333333u)
    TRP(t4, t6, 2, 0x33333333u)  TRP(t5, t7, 2, 0x33333333u)
    TRP(t8, t10, 2, 0x33333333u) TRP(t9, t11, 2, 0x33333333u)
    TRP(t12, t14, 2, 0x33333333u) TRP(t13, t15, 2, 0x33333333u)
    TRP(t16, t18, 2, 0x33333333u) TRP(t17, t19, 2, 0x33333333u)
    TRP(t20, t22, 2, 0x33333333u) TRP(t21, t23, 2, 0x33333333u)
    TRP(t24, t26, 2, 0x33333333u) TRP(t25, t27, 2, 0x33333333u)
    TRP(t28, t30, 2, 0x33333333u) TRP(t29, t31, 2, 0x33333333u)
    TRP(t0, t1, 1, 0x55555555u)  TRP(t2, t3, 1, 0x55555555u)
    TRP(t4, t5, 1, 0x55555555u)  TRP(t6, t7, 1, 0x55555555u)
    TRP(t8, t9, 1, 0x55555555u)  TRP(t10, t11, 1, 0x55555555u)
    TRP(t12, t13, 1, 0x55555555u) TRP(t14, t15, 1, 0x55555555u)
    TRP(t16, t17, 1, 0x55555555u) TRP(t18, t19, 1, 0x55555555u)
    TRP(t20, t21, 1, 0x55555555u) TRP(t22, t23, 1, 0x55555555u)
    TRP(t24, t25, 1, 0x55555555u) TRP(t26, t27, 1, 0x55555555u)
    TRP(t28, t29, 1, 0x55555555u) TRP(t30, t31, 1, 0x55555555u)

    // ---- 2-bit rank-count binary search (16 steps, MSB pair first) ----
    unsigned T = 0u, E = 0xffffffffu;
    int gcnt = 0;
    SEL2(t31, t30, 1u << 31, 1u << 30)
    SEL2(t29, t28, 1u << 29, 1u << 28)
    SEL2(t27, t26, 1u << 27, 1u << 26)
    SEL2(t25, t24, 1u << 25, 1u << 24)
    SEL2(t23, t22, 1u << 23, 1u << 22)
    SEL2(t21, t20, 1u << 21, 1u << 20)
    SEL2(t19, t18, 1u << 19, 1u << 18)
    SEL2(t17, t16, 1u << 17, 1u << 16)
    SEL2(t15, t14, 1u << 15, 1u << 14)
    SEL2(t13, t12, 1u << 13, 1u << 12)
    SEL2(t11, t10, 1u << 11, 1u << 10)
    SEL2(t9,  t8,  1u << 9,  1u << 8)
    SEL2(t7,  t6,  1u << 7,  1u << 6)
    SEL2(t5,  t4,  1u << 5,  1u << 4)
    SEL2(t3,  t2,  1u << 3,  1u << 2)
    SEL2(t1,  t0,  2u,       1u)
sel_done: ;
    // threshold = min{u >= T}  (== exact KK-th largest; tie-exact)
    {
        unsigned mn = 0xffffffffu;
        MNU(u0) MNU(u1) MNU(u2) MNU(u3) MNU(u4) MNU(u5) MNU(u6) MNU(u7)
        MNU(u8) MNU(u9) MNU(u10) MNU(u11) MNU(u12) MNU(u13) MNU(u14) MNU(u15)
        MNU(u16) MNU(u17) MNU(u18) MNU(u19) MNU(u20) MNU(u21) MNU(u22) MNU(u23)
        MNU(u24) MNU(u25) MNU(u26) MNU(u27) MNU(u28) MNU(u29) MNU(u30) MNU(u31)
#pragma unroll
        for (int off = 32; off >= 1; off >>= 1) {
            const unsigned o = (unsigned)__shfl_xor((int)mn, off);
            mn = o < mn ? o : mn;
        }
        T = mn;
    }

    // ---- softmax numerators; bf16 P in-place into hi-16 of score words ----
    float lsum = 0.f;
    EXG(u0, u1, u2, u3, 0 * 256)    EXG(u4, u5, u6, u7, 1 * 256)
    EXG(u8, u9, u10, u11, 2 * 256)  EXG(u12, u13, u14, u15, 3 * 256)
    EXG(u16, u17, u18, u19, 4 * 256) EXG(u20, u21, u22, u23, 5 * 256)
    EXG(u24, u25, u26, u27, 6 * 256) EXG(u28, u29, u30, u31, 7 * 256)
#pragma unroll
    for (int off = 32; off >= 1; off >>= 1) lsum += __shfl_xor(lsum, off);
    return 1.f / lsum;
}

// ---------------------------------------------------------------------------
// Fused attention R17 — R13 geometry (16 waves, 1 block/CU), 2-bit select.
// Single variable vs R13's 565us.
// ---------------------------------------------------------------------------
__global__ __launch_bounds__(1024, 4)
void attn_kernel(const unsigned short* __restrict__ Qh, const unsigned short* __restrict__ Ql,
                 const unsigned short* __restrict__ Kh, const unsigned short* __restrict__ Kl,
                 const unsigned short* __restrict__ Vt,
                 unsigned short* __restrict__ AOh, unsigned short* __restrict__ AOl)
{
    extern __shared__ __align__(16) char smem[];
    unsigned* S = (unsigned*)smem;          // [16][SSTR] ord scores / bf16-P overlay
    float* Opart = (float*)smem;            // overlay [16][16][64] after PV reads done

    const int tid  = threadIdx.x;
    const int lane = tid & 63;
    const int w    = tid >> 6;              // 0..15
    const int q15  = lane & 15;
    const int quad = lane >> 4;

    // XCD swizzle: 4 heads per XCD -> K+V working set ~3 MB, fits 4 MB L2
    const int blk = blockIdx.x;
    const int bh  = (blk & 7) * 4 + ((blk >> 3) & 3);
    const int q0  = (blk >> 5) * 16;

    // ---- Q B-frags direct from global ----
    const size_t qrow = ((size_t)bh * S_LEN + q0 + q15) * HDIM;
    const bf16x8 bqh0 = *(const bf16x8*)(Qh + qrow + quad * 8);
    const bf16x8 bqh1 = *(const bf16x8*)(Qh + qrow + 32 + quad * 8);
    const bf16x8 bql0 = *(const bf16x8*)(Ql + qrow + quad * 8);
    const bf16x8 bql1 = *(const bf16x8*)(Ql + qrow + 32 + quad * 8);

    const size_t kbase = (size_t)bh * S_LEN * HDIM;

    // ---- phase 1: QK^T, 8 key-tiles per wave, straight to LDS ----
#pragma unroll 4
    for (int t = 0; t < 8; ++t) {
        const int key = w * 128 + t * 16 + q15;     // A-frag m
        const unsigned short* kh = Kh + kbase + (size_t)key * HDIM + quad * 8;
        const unsigned short* kl = Kl + kbase + (size_t)key * HDIM + quad * 8;
        const bf16x8 akh0 = *(const bf16x8*)(kh);
        const bf16x8 akh1 = *(const bf16x8*)(kh + 32);
        const bf16x8 akl0 = *(const bf16x8*)(kl);
        const bf16x8 akl1 = *(const bf16x8*)(kl + 32);
        f32x4 c = {0.f, 0.f, 0.f, 0.f};
        c = __builtin_amdgcn_mfma_f32_16x16x32_bf16(akh0, bqh0, c, 0, 0, 0);
        c = __builtin_amdgcn_mfma_f32_16x16x32_bf16(akh1, bqh1, c, 0, 0, 0);
        c = __builtin_amdgcn_mfma_f32_16x16x32_bf16(akh0, bql0, c, 0, 0, 0);
        c = __builtin_amdgcn_mfma_f32_16x16x32_bf16(akh1, bql1, c, 0, 0, 0);
        c = __builtin_amdgcn_mfma_f32_16x16x32_bf16(akl0, bqh0, c, 0, 0, 0);
        c = __builtin_amdgcn_mfma_f32_16x16x32_bf16(akl1, bqh1, c, 0, 0, 0);
        c = c * 0.125f;
        // C-layout: col=lane&15=q(row of S), row-in-tile=quad*4+reg=key(col)
        uint4 o;
        o.x = f2ord(c[0]); o.y = f2ord(c[1]); o.z = f2ord(c[2]); o.w = f2ord(c[3]);
        *(uint4*)(S + q15 * SSTR + w * 128 + t * 16 + quad * 4) = o;
    }
    __syncthreads();   // full [16][2048] score matrix visible

    // ---- phase 2: one row per wave: select + softmax, in-place bf16 P ----
    const float invd = row_pass(S + w * SSTR, lane);
    __syncthreads();   // all P visible

    // ---- phase 3: dense PV via bf16 MFMA, wave w keys [128w,128w+128) ----
    {
        f32x4 oacc[4];
#pragma unroll
        for (int ht = 0; ht < 4; ++ht) oacc[ht] = (f32x4){0.f, 0.f, 0.f, 0.f};
        const size_t vtb = (size_t)bh * HDIM * S_LEN;
        const unsigned* Srow = S + q15 * SSTR;
#pragma unroll 2
        for (int ks = 0; ks < 4; ++ks) {
            const int key0 = w * 128 + ks * 32 + quad * 8;
            const uint4 a0 = *(const uint4*)(Srow + key0);
            const uint4 a1 = *(const uint4*)(Srow + key0 + 4);
            const bf16x8 ap = pack_hi8(a0, a1);                      // A[m=q][k=key]
#pragma unroll
            for (int ht = 0; ht < 4; ++ht) {
                const int hd = ht * 16 + q15;                        // B[k=key][n=hd]
                const bf16x8 bv = *(const bf16x8*)(Vt + vtb + (size_t)hd * S_LEN + key0);
                oacc[ht] = __builtin_amdgcn_mfma_f32_16x16x32_bf16(ap, bv, oacc[ht], 0, 0, 0);
            }
        }
        __syncthreads();   // all P reads done; score region dead -> Opart live
        // D[m=q][n=hd]: col=lane&15=hd-in-tile, row=quad*4+reg=q
#pragma unroll
        for (int ht = 0; ht < 4; ++ht)
#pragma unroll
            for (int rg = 0; rg < 4; ++rg)
                Opart[w * 1024 + (quad * 4 + rg) * 64 + ht * 16 + q15] = oacc[ht][rg];
    }
    __syncthreads();

    // ---- final: wave w reduces 16 partials for row w, writes AO hi/lo ----
    {
        float s = 0.f;
#pragma unroll
        for (int ww = 0; ww < 16; ++ww)
            s += Opart[ww * 1024 + w * 64 + lane];
        const int b = bh >> 4, h = bh & 15;
        const float o = s * invd;
        const size_t i = ((size_t)(b * S_LEN + q0 + w)) * DMODEL + h * HDIM + lane;
        const unsigned short oh = f2bf(o);
        AOh[i] = oh; AOl[i] = f2bf(o - bf2f(oh));
    }
}

// ---------------------------------------------------------------------------
extern "C" void kernel_launch(void* const* d_in, const int* in_sizes, int n_in,
                              void* d_out, int out_size, void* d_ws, size_t ws_size,
                              hipStream_t stream)
{
    const float* X  = (const float*)d_in[0];
    const float* Wq = (const float*)d_in[1];
    const float* bq = (const float*)d_in[2];
    const float* Wk = (const float*)d_in[3];
    const float* bk = (const float*)d_in[4];
    const float* Wv = (const float*)d_in[5];
    const float* bv = (const float*)d_in[6];
    const float* Wo = (const float*)d_in[7];
    const float* bo = (const float*)d_in[8];

    char* p = (char*)d_ws;
    const size_t NEL = (size_t)BHC * S_LEN * HDIM;   // 4,194,304
    unsigned short* Q16h = (unsigned short*)p; p += NEL * 2;
    unsigned short* Q16l = (unsigned short*)p; p += NEL * 2;
    unsigned short* K16h = (unsigned short*)p; p += NEL * 2;
    unsigned short* K16l = (unsigned short*)p; p += NEL * 2;
    unsigned short* Vb16 = (unsigned short*)p; p += NEL * 2;
    unsigned short* Vt16 = (unsigned short*)p; p += NEL * 2;
    unsigned short* Xh   = (unsigned short*)p; p += NEL * 2;
    unsigned short* Xl   = (unsigned short*)p; p += NEL * 2;
    unsigned short* AOh  = (unsigned short*)p; p += NEL * 2;
    unsigned short* AOl  = (unsigned short*)p; p += NEL * 2;
    unsigned short* Wqh  = (unsigned short*)p; p += DMODEL * DMODEL * 2;
    unsigned short* Wql  = (unsigned short*)p; p += DMODEL * DMODEL * 2;
    unsigned short* Wkh  = (unsigned short*)p; p += DMODEL * DMODEL * 2;
    unsigned short* Wkl  = (unsigned short*)p; p += DMODEL * DMODEL * 2;
    unsigned short* Wvh  = (unsigned short*)p; p += DMODEL * DMODEL * 2;
    unsigned short* Wvl  = (unsigned short*)p; p += DMODEL * DMODEL * 2;
    unsigned short* Woh  = (unsigned short*)p; p += DMODEL * DMODEL * 2;
    unsigned short* Wol  = (unsigned short*)p; p += DMODEL * DMODEL * 2;

    const int attn_lds = 16 * SSTR * 4;   // 131,328 B -> 1 block/CU
    hipFuncSetAttribute((const void*)attn_kernel,
                        hipFuncAttributeMaxDynamicSharedMemorySize, attn_lds);

    const int X4 = (int)(NEL / 4);
    const int W4 = DMODEL * DMODEL / 4;

    // ---- input splits ----
    split32<<<(X4 + 255) / 256, 256, 0, stream>>>(X,  Xh,  Xl,  X4);
    split32<<<(W4 + 255) / 256, 256, 0, stream>>>(Wq, Wqh, Wql, W4);
    split32<<<(W4 + 255) / 256, 256, 0, stream>>>(Wk, Wkh, Wkl, W4);
    split32<<<(W4 + 255) / 256, 256, 0, stream>>>(Wv, Wvh, Wvl, W4);
    split32<<<(W4 + 255) / 256, 256, 0, stream>>>(Wo, Woh, Wol, W4);

    // ---- projections ----
    const dim3 ggrid(16, 32, 1);
    gemm_mfma<<<ggrid, 256, 0, stream>>>(Xh, Xl, Wqh, Wql, bq, Q16h, Q16l, 2);
    gemm_mfma<<<ggrid, 256, 0, stream>>>(Xh, Xl, Wkh, Wkl, bk, K16h, K16l, 2);
    gemm_mfma<<<ggrid, 256, 0, stream>>>(Xh, Xl, Wvh, Wvl, bv, Vb16, nullptr, 3);
    transpose_v16<<<dim3(32, 32, 1), 256, 0, stream>>>(Vb16, Vt16);

    // ---- fused attention (R17: 2-bit radix select, half the chain) ----
    attn_kernel<<<4096, 1024, attn_lds, stream>>>(Q16h, Q16l, K16h, K16l, Vt16, AOh, AOl);

    // ---- output projection ----
    gemm_mfma<<<ggrid, 256, 0, stream>>>(AOh, AOl, Woh, Wol, bo, d_out, nullptr, 0);
}

// Round 13
// 761.991 us; speedup vs baseline: 2.2740x; 1.0555x over previous
//
#include <hip/hip_runtime.h>
#include <math.h>

#define S_LEN 2048
#define NH 16
#define HDIM 64
#define BATCH 2
#define BHC 32          // BATCH*NH
#define KK 409          // int(2048 * (1.0 - 0.8)) per reference float math
#define DMODEL 1024

typedef __attribute__((ext_vector_type(8))) short bf16x8;   // 8 bf16 in 4 VGPRs
typedef __attribute__((ext_vector_type(4))) float f32x4;

// LDS-resident score matrix. 16 rows * 2052 * 4 B = 131,328 B -> 1 block/CU.
// 2052 % 32 == 4 -> no hot bank on any access pattern below.
#define SSTR 2052
#define T_STR  40       // bf16 LDS tile row stride for gemm: 80 B, 16B-aligned

__device__ __forceinline__ unsigned f2ord(float f) {
    unsigned u = __float_as_uint(f);
    return (u & 0x80000000u) ? ~u : (u | 0x80000000u);
}
__device__ __forceinline__ float ord2f(unsigned v) {
    unsigned u = (v & 0x80000000u) ? (v & 0x7fffffffu) : ~v;
    return __uint_as_float(u);
}
__device__ __forceinline__ unsigned short f2bf(float f) {   // RNE
    unsigned u = __float_as_uint(f);
    u += 0x7fffu + ((u >> 16) & 1u);
    return (unsigned short)(u >> 16);
}
__device__ __forceinline__ float bf2f(unsigned short h) {
    return __uint_as_float(((unsigned)h) << 16);
}

// ---------------------------------------------------------------------------
// DPP wave64 reductions (rocPRIM recipe): 6 VALU mov_dpp+op pairs, result in
// lane 63, broadcast via readlane -> SGPR-uniform.  No ballots, no SALU
// chains, no ds_bpermute.  row_shr:1/2/4/8 then row_bcast:15/31.
// ---------------------------------------------------------------------------
__device__ __forceinline__ int wsum_dpp(int x) {
    x += __builtin_amdgcn_update_dpp(0, x, 0x111, 0xf, 0xf, false);
    x += __builtin_amdgcn_update_dpp(0, x, 0x112, 0xf, 0xf, false);
    x += __builtin_amdgcn_update_dpp(0, x, 0x114, 0xf, 0xe, false);
    x += __builtin_amdgcn_update_dpp(0, x, 0x118, 0xf, 0xc, false);
    x += __builtin_amdgcn_update_dpp(0, x, 0x142, 0xa, 0xf, false);
    x += __builtin_amdgcn_update_dpp(0, x, 0x143, 0xc, 0xf, false);
    return __builtin_amdgcn_readlane(x, 63);
}
__device__ __forceinline__ unsigned wmax_dpp(unsigned x) {
    unsigned t;
    t = (unsigned)__builtin_amdgcn_update_dpp(0, (int)x, 0x111, 0xf, 0xf, false); x = x > t ? x : t;
    t = (unsigned)__builtin_amdgcn_update_dpp(0, (int)x, 0x112, 0xf, 0xf, false); x = x > t ? x : t;
    t = (unsigned)__builtin_amdgcn_update_dpp(0, (int)x, 0x114, 0xf, 0xf, false); x = x > t ? x : t;
    t = (unsigned)__builtin_amdgcn_update_dpp(0, (int)x, 0x118, 0xf, 0xf, false); x = x > t ? x : t;
    t = (unsigned)__builtin_amdgcn_update_dpp(0, (int)x, 0x142, 0xf, 0xf, false); x = x > t ? x : t;
    t = (unsigned)__builtin_amdgcn_update_dpp(0, (int)x, 0x143, 0xf, 0xf, false); x = x > t ? x : t;
    return (unsigned)__builtin_amdgcn_readlane((int)x, 63);
}
__device__ __forceinline__ unsigned wmin_dpp(unsigned x) {
    unsigned t;
    t = (unsigned)__builtin_amdgcn_update_dpp((int)0xffffffff, (int)x, 0x111, 0xf, 0xf, false); x = x < t ? x : t;
    t = (unsigned)__builtin_amdgcn_update_dpp((int)0xffffffff, (int)x, 0x112, 0xf, 0xf, false); x = x < t ? x : t;
    t = (unsigned)__builtin_amdgcn_update_dpp((int)0xffffffff, (int)x, 0x114, 0xf, 0xf, false); x = x < t ? x : t;
    t = (unsigned)__builtin_amdgcn_update_dpp((int)0xffffffff, (int)x, 0x118, 0xf, 0xf, false); x = x < t ? x : t;
    t = (unsigned)__builtin_amdgcn_update_dpp((int)0xffffffff, (int)x, 0x142, 0xf, 0xf, false); x = x < t ? x : t;
    t = (unsigned)__builtin_amdgcn_update_dpp((int)0xffffffff, (int)x, 0x143, 0xf, 0xf, false); x = x < t ? x : t;
    return (unsigned)__builtin_amdgcn_readlane((int)x, 63);
}
__device__ __forceinline__ float fsum_dpp(float x) {
    x += __int_as_float(__builtin_amdgcn_update_dpp(0, __float_as_int(x), 0x111, 0xf, 0xf, false));
    x += __int_as_float(__builtin_amdgcn_update_dpp(0, __float_as_int(x), 0x112, 0xf, 0xf, false));
    x += __int_as_float(__builtin_amdgcn_update_dpp(0, __float_as_int(x), 0x114, 0xf, 0xe, false));
    x += __int_as_float(__builtin_amdgcn_update_dpp(0, __float_as_int(x), 0x118, 0xf, 0xc, false));
    x += __int_as_float(__builtin_amdgcn_update_dpp(0, __float_as_int(x), 0x142, 0xa, 0xf, false));
    x += __int_as_float(__builtin_amdgcn_update_dpp(0, __float_as_int(x), 0x143, 0xc, 0xf, false));
    return __int_as_float(__builtin_amdgcn_readlane(__float_as_int(x), 63));
}

// ---------------------------------------------------------------------------
// fp32 -> bf16 hi/lo split (vectorized float4 / ushort4), n4 = elements/4
// ---------------------------------------------------------------------------
__global__ __launch_bounds__(256)
void split32(const float* __restrict__ in, unsigned short* __restrict__ hi,
             unsigned short* __restrict__ lo, int n4)
{
    const int i = blockIdx.x * 256 + threadIdx.x;
    if (i < n4) {
        const float4 v = ((const float4*)in)[i];
        ushort4 h, l;
        h.x = f2bf(v.x); l.x = f2bf(v.x - bf2f(h.x));
        h.y = f2bf(v.y); l.y = f2bf(v.y - bf2f(h.y));
        h.z = f2bf(v.z); l.z = f2bf(v.z - bf2f(h.z));
        h.w = f2bf(v.w); l.w = f2bf(v.w - bf2f(h.w));
        ((ushort4*)hi)[i] = h;
        ((ushort4*)lo)[i] = l;
    }
}

// ---------------------------------------------------------------------------
// LDS-staged split-bf16 3-pass MFMA GEMM (unchanged — R8 banked structure).
// ---------------------------------------------------------------------------
__global__ __launch_bounds__(256)
void gemm_mfma(const unsigned short* __restrict__ Ah, const unsigned short* __restrict__ Al,
               const unsigned short* __restrict__ Bh, const unsigned short* __restrict__ Bl,
               const float* __restrict__ bias, void* __restrict__ out0,
               void* __restrict__ out1, int mode)
{
    __shared__ __align__(16) unsigned short sAh[128 * T_STR];
    __shared__ __align__(16) unsigned short sAl[128 * T_STR];
    __shared__ __align__(16) unsigned short sBh[64 * T_STR];
    __shared__ __align__(16) unsigned short sBl[64 * T_STR];

    const int tid  = threadIdx.x;
    const int lane = tid & 63;
    const int w    = tid >> 6;
    const int q15  = lane & 15;
    const int quad = lane >> 4;
    const int n0b = blockIdx.x * 64;
    const int m0b = blockIdx.y * 128;
    const int wm = (w >> 1) * 64;
    const int wn = (w & 1) * 32;

    const int ar0 = tid >> 2, aks0 = (tid & 3) * 8;
    const int ar1 = (tid + 256) >> 2, aks1 = aks0;
    const int br = tid >> 2, bks = (tid & 3) * 8;

    const unsigned short* gAh0 = Ah + (size_t)(m0b + ar0) * 1024 + aks0;
    const unsigned short* gAh1 = Ah + (size_t)(m0b + ar1) * 1024 + aks1;
    const unsigned short* gAl0 = Al + (size_t)(m0b + ar0) * 1024 + aks0;
    const unsigned short* gAl1 = Al + (size_t)(m0b + ar1) * 1024 + aks1;
    const unsigned short* gBh = Bh + (size_t)(n0b + br) * 1024 + bks;
    const unsigned short* gBl = Bl + (size_t)(n0b + br) * 1024 + bks;

    f32x4 acc[4][2];
#pragma unroll
    for (int mt = 0; mt < 4; ++mt)
#pragma unroll
        for (int nt = 0; nt < 2; ++nt) acc[mt][nt] = (f32x4){0.f, 0.f, 0.f, 0.f};

#pragma unroll 1
    for (int k0 = 0; k0 < 1024; k0 += 32) {
        const bf16x8 vah0 = *(const bf16x8*)(gAh0 + k0);
        const bf16x8 vah1 = *(const bf16x8*)(gAh1 + k0);
        const bf16x8 val0 = *(const bf16x8*)(gAl0 + k0);
        const bf16x8 val1 = *(const bf16x8*)(gAl1 + k0);
        const bf16x8 vbh  = *(const bf16x8*)(gBh + k0);
        const bf16x8 vbl  = *(const bf16x8*)(gBl + k0);
        __syncthreads();
        *(bf16x8*)(sAh + ar0 * T_STR + aks0) = vah0;
        *(bf16x8*)(sAh + ar1 * T_STR + aks1) = vah1;
        *(bf16x8*)(sAl + ar0 * T_STR + aks0) = val0;
        *(bf16x8*)(sAl + ar1 * T_STR + aks1) = val1;
        *(bf16x8*)(sBh + br * T_STR + bks) = vbh;
        *(bf16x8*)(sBl + br * T_STR + bks) = vbl;
        __syncthreads();

        bf16x8 fbh[2], fbl[2];
#pragma unroll
        for (int nt = 0; nt < 2; ++nt) {
            fbh[nt] = *(const bf16x8*)(sBh + (wn + nt * 16 + q15) * T_STR + quad * 8);
            fbl[nt] = *(const bf16x8*)(sBl + (wn + nt * 16 + q15) * T_STR + quad * 8);
        }
#pragma unroll
        for (int mt = 0; mt < 4; ++mt) {
            const bf16x8 fah = *(const bf16x8*)(sAh + (wm + mt * 16 + q15) * T_STR + quad * 8);
            const bf16x8 fal = *(const bf16x8*)(sAl + (wm + mt * 16 + q15) * T_STR + quad * 8);
#pragma unroll
            for (int nt = 0; nt < 2; ++nt) {
                acc[mt][nt] = __builtin_amdgcn_mfma_f32_16x16x32_bf16(fah, fbh[nt], acc[mt][nt], 0, 0, 0);
                acc[mt][nt] = __builtin_amdgcn_mfma_f32_16x16x32_bf16(fah, fbl[nt], acc[mt][nt], 0, 0, 0);
                acc[mt][nt] = __builtin_amdgcn_mfma_f32_16x16x32_bf16(fal, fbh[nt], acc[mt][nt], 0, 0, 0);
            }
        }
    }

#pragma unroll
    for (int nt = 0; nt < 2; ++nt) {
        const int n = n0b + wn + nt * 16 + q15;
        const float bv = bias[n];
#pragma unroll
        for (int mt = 0; mt < 4; ++mt) {
            const int mb = m0b + wm + mt * 16 + quad * 4;
#pragma unroll
            for (int rg = 0; rg < 4; ++rg) {
                const int m = mb + rg;
                const float o = acc[mt][nt][rg] + bv;
                if (mode == 0) {
                    ((float*)out0)[(size_t)m * 1024 + n] = o;
                } else {
                    const int b = m >> 11, s = m & 2047;
                    const int h = n >> 6, hd = n & 63;
                    const size_t base = ((size_t)((b * NH + h) * S_LEN + s)) * HDIM + hd;
                    if (mode == 3) {
                        ((unsigned short*)out0)[base] = f2bf(o);
                    } else {
                        const unsigned short oh = f2bf(o);
                        ((unsigned short*)out0)[base] = oh;
                        ((unsigned short*)out1)[base] = f2bf(o - bf2f(oh));
                    }
                }
            }
        }
    }
}

// ---------------------------------------------------------------------------
// V bf16 [bh][s][64] -> Vt bf16 [bh][64][2048]
// ---------------------------------------------------------------------------
__global__ __launch_bounds__(256)
void transpose_v16(const unsigned short* __restrict__ V, unsigned short* __restrict__ Vt)
{
    __shared__ unsigned short t[64][72];
    const int tid = threadIdx.x;
    const int s0 = blockIdx.x * 64;
    const int bh = blockIdx.y;
    const unsigned short* Vb = V + (size_t)bh * S_LEN * HDIM;
#pragma unroll
    for (int i = 0; i < 4; ++i) {
        const int f = tid + i * 256;
        const int s = f >> 4;
        const int hq = (f & 15) * 4;
        const ushort4 v = *(const ushort4*)(Vb + (size_t)(s0 + s) * HDIM + hq);
        t[s][hq + 0] = v.x; t[s][hq + 1] = v.y; t[s][hq + 2] = v.z; t[s][hq + 3] = v.w;
    }
    __syncthreads();
    unsigned short* Vtb = Vt + (size_t)bh * HDIM * S_LEN;
#pragma unroll
    for (int i = 0; i < 4; ++i) {
        const int f = tid + i * 256;
        const int hd = f >> 4;
        const int sq = (f & 15) * 4;
        ushort4 v;
        v.x = t[sq + 0][hd]; v.y = t[sq + 1][hd];
        v.z = t[sq + 2][hd]; v.w = t[sq + 3][hd];
        *(ushort4*)(Vtb + (size_t)hd * S_LEN + s0 + sq) = v;
    }
}

__device__ __forceinline__ bf16x8 pack_hi8(const uint4 a0, const uint4 a1)
{
    union { unsigned u[4]; bf16x8 v; } c;
    c.u[0] = (a0.x >> 16) | (a0.y & 0xffff0000u);
    c.u[1] = (a0.z >> 16) | (a0.w & 0xffff0000u);
    c.u[2] = (a1.x >> 16) | (a1.y & 0xffff0000u);
    c.u[3] = (a1.z >> 16) | (a1.w & 0xffff0000u);
    return c.v;
}

// ---------------------------------------------------------------------------
// R18 phase-2 row pass — R13's proven 1-bit rank-count select, with ALL
// cross-lane reductions converted to DPP (select wave-sums, row max, final
// min, lsum).  (R16: shfl/ds_bpermute is the most expensive primitive;
// R17: more ballots = slower.  DPP is the cheapest: 6 VALU pairs, no LDS,
// no SALU chains.)  Semantics byte-identical to R13's verified select.
// ---------------------------------------------------------------------------
#define TRP(AK, AKJ, J, M) { const unsigned _t = (((AK) >> (J)) ^ (AKJ)) & (M); \
                             (AK) ^= _t << (J); (AKJ) ^= _t; }
#define UMX(A, B) ((A) > (B) ? (A) : (B))

#define SELSTEP(TB, BITV) { \
    const unsigned eb = E & (TB); \
    const int cnt = gcnt + wsum_dpp(__builtin_popcount(eb)); \
    if (cnt >= KK) { T |= (BITV); E = eb; if (cnt == KK) goto sel_done; } \
    else { gcnt = cnt; E &= ~(TB); } \
}

#define MNU(U) { const unsigned _v = (U) >= T ? (U) : 0xffffffffu; mn = _v < mn ? _v : mn; }

#define EXG(UA, UB, UC, UD, OFF) { \
    const float ea = (UA) >= T ? __expf(ord2f(UA) - mx) : 0.f; \
    const float eb_ = (UB) >= T ? __expf(ord2f(UB) - mx) : 0.f; \
    const float ec = (UC) >= T ? __expf(ord2f(UC) - mx) : 0.f; \
    const float ed = (UD) >= T ? __expf(ord2f(UD) - mx) : 0.f; \
    uint4 wv; \
    wv.x = ((unsigned)f2bf(ea)) << 16; \
    wv.y = ((unsigned)f2bf(eb_)) << 16; \
    wv.z = ((unsigned)f2bf(ec)) << 16; \
    wv.w = ((unsigned)f2bf(ed)) << 16; \
    *(uint4*)(R + (OFF) + lane * 4) = wv; \
    lsum += ea + eb_ + ec + ed; }

__device__ __forceinline__ float row_pass(unsigned* R, const int lane)
{
    // ---- load the lane's 32-element slice: 8x ds_read_b128, all named ----
    const uint4 q0 = *(const uint4*)(R + 0 * 256 + lane * 4);
    const uint4 q1 = *(const uint4*)(R + 1 * 256 + lane * 4);
    const uint4 q2 = *(const uint4*)(R + 2 * 256 + lane * 4);
    const uint4 q3 = *(const uint4*)(R + 3 * 256 + lane * 4);
    const uint4 q4 = *(const uint4*)(R + 4 * 256 + lane * 4);
    const uint4 q5 = *(const uint4*)(R + 5 * 256 + lane * 4);
    const uint4 q6 = *(const uint4*)(R + 6 * 256 + lane * 4);
    const uint4 q7 = *(const uint4*)(R + 7 * 256 + lane * 4);
    const unsigned u0  = q0.x, u1  = q0.y, u2  = q0.z, u3  = q0.w;
    const unsigned u4  = q1.x, u5  = q1.y, u6  = q1.z, u7  = q1.w;
    const unsigned u8  = q2.x, u9  = q2.y, u10 = q2.z, u11 = q2.w;
    const unsigned u12 = q3.x, u13 = q3.y, u14 = q3.z, u15 = q3.w;
    const unsigned u16 = q4.x, u17 = q4.y, u18 = q4.z, u19 = q4.w;
    const unsigned u20 = q5.x, u21 = q5.y, u22 = q5.z, u23 = q5.w;
    const unsigned u24 = q6.x, u25 = q6.y, u26 = q6.z, u27 = q6.w;
    const unsigned u28 = q7.x, u29 = q7.y, u30 = q7.z, u31 = q7.w;

    // ---- row max (tree + DPP wave reduce) ----
    const unsigned a0 = UMX(u0, u1),  a1 = UMX(u2, u3),  a2 = UMX(u4, u5),  a3 = UMX(u6, u7);
    const unsigned a4 = UMX(u8, u9),  a5 = UMX(u10, u11), a6 = UMX(u12, u13), a7 = UMX(u14, u15);
    const unsigned a8 = UMX(u16, u17), a9 = UMX(u18, u19), a10 = UMX(u20, u21), a11 = UMX(u22, u23);
    const unsigned a12 = UMX(u24, u25), a13 = UMX(u26, u27), a14 = UMX(u28, u29), a15 = UMX(u30, u31);
    const unsigned b0 = UMX(a0, a1), b1 = UMX(a2, a3), b2 = UMX(a4, a5), b3 = UMX(a6, a7);
    const unsigned b4 = UMX(a8, a9), b5 = UMX(a10, a11), b6 = UMX(a12, a13), b7 = UMX(a14, a15);
    const unsigned c0 = UMX(b0, b1), c1 = UMX(b2, b3), c2 = UMX(b4, b5), c3 = UMX(b6, b7);
    const unsigned umx = wmax_dpp(UMX(UMX(c0, c1), UMX(c2, c3)));
    const float mx = ord2f(umx);

    // ---- 32x32 bit transpose: t{b} bit j = bit b of u{j} ----
    unsigned t0 = u0,  t1 = u1,  t2 = u2,  t3 = u3,  t4 = u4,  t5 = u5,  t6 = u6,  t7 = u7;
    unsigned t8 = u8,  t9 = u9,  t10 = u10, t11 = u11, t12 = u12, t13 = u13, t14 = u14, t15 = u15;
    unsigned t16 = u16, t17 = u17, t18 = u18, t19 = u19, t20 = u20, t21 = u21, t22 = u22, t23 = u23;
    unsigned t24 = u24, t25 = u25, t26 = u26, t27 = u27, t28 = u28, t29 = u29, t30 = u30, t31 = u31;
    TRP(t0, t16, 16, 0x0000FFFFu) TRP(t1, t17, 16, 0x0000FFFFu)
    TRP(t2, t18, 16, 0x0000FFFFu) TRP(t3, t19, 16, 0x0000FFFFu)
    TRP(t4, t20, 16, 0x0000FFFFu) TRP(t5, t21, 16, 0x0000FFFFu)
    TRP(t6, t22, 16, 0x0000FFFFu) TRP(t7, t23, 16, 0x0000FFFFu)
    TRP(t8, t24, 16, 0x0000FFFFu) TRP(t9, t25, 16, 0x0000FFFFu)
    TRP(t10, t26, 16, 0x0000FFFFu) TRP(t11, t27, 16, 0x0000FFFFu)
    TRP(t12, t28, 16, 0x0000FFFFu) TRP(t13, t29, 16, 0x0000FFFFu)
    TRP(t14, t30, 16, 0x0000FFFFu) TRP(t15, t31, 16, 0x0000FFFFu)
    TRP(t0, t8, 8, 0x00FF00FFu)  TRP(t1, t9, 8, 0x00FF00FFu)
    TRP(t2, t10, 8, 0x00FF00FFu) TRP(t3, t11, 8, 0x00FF00FFu)
    TRP(t4, t12, 8, 0x00FF00FFu) TRP(t5, t13, 8, 0x00FF00FFu)
    TRP(t6, t14, 8, 0x00FF00FFu) TRP(t7, t15, 8, 0x00FF00FFu)
    TRP(t16, t24, 8, 0x00FF00FFu) TRP(t17, t25, 8, 0x00FF00FFu)
    TRP(t18, t26, 8, 0x00FF00FFu) TRP(t19, t27, 8, 0x00FF00FFu)
    TRP(t20, t28, 8, 0x00FF00FFu) TRP(t21, t29, 8, 0x00FF00FFu)
    TRP(t22, t30, 8, 0x00FF00FFu) TRP(t23, t31, 8, 0x00FF00FFu)
    TRP(t0, t4, 4, 0x0F0F0F0Fu)  TRP(t1, t5, 4, 0x0F0F0F0Fu)
    TRP(t2, t6, 4, 0x0F0F0F0Fu)  TRP(t3, t7, 4, 0x0F0F0F0Fu)
    TRP(t8, t12, 4, 0x0F0F0F0Fu) TRP(t9, t13, 4, 0x0F0F0F0Fu)
    TRP(t10, t14, 4, 0x0F0F0F0Fu) TRP(t11, t15, 4, 0x0F0F0F0Fu)
    TRP(t16, t20, 4, 0x0F0F0F0Fu) TRP(t17, t21, 4, 0x0F0F0F0Fu)
    TRP(t18, t22, 4, 0x0F0F0F0Fu) TRP(t19, t23, 4, 0x0F0F0F0Fu)
    TRP(t24, t28, 4, 0x0F0F0F0Fu) TRP(t25, t29, 4, 0x0F0F0F0Fu)
    TRP(t26, t30, 4, 0x0F0F0F0Fu) TRP(t27, t31, 4, 0x0F0F0F0Fu)
    TRP(t0, t2, 2, 0x33333333u)  TRP(t1, t3, 2, 0x33333333u)
    TRP(t4, t6, 2, 0x33333333u)  TRP(t5, t7, 2, 0x33333333u)
    TRP(t8, t10, 2, 0x33333333u) TRP(t9, t11, 2, 0x33333333u)
    TRP(t12, t14, 2, 0x33333333u) TRP(t13, t15, 2, 0x33333333u)
    TRP(t16, t18, 2, 0x33333333u) TRP(t17, t19, 2, 0x33333333u)
    TRP(t20, t22, 2, 0x33333333u) TRP(t21, t23, 2, 0x33333333u)
    TRP(t24, t26, 2, 0x33333333u) TRP(t25, t27, 2, 0x33333333u)
    TRP(t28, t30, 2, 0x33333333u) TRP(t29, t31, 2, 0x33333333u)
    TRP(t0, t1, 1, 0x55555555u)  TRP(t2, t3, 1, 0x55555555u)
    TRP(t4, t5, 1, 0x55555555u)  TRP(t6, t7, 1, 0x55555555u)
    TRP(t8, t9, 1, 0x55555555u)  TRP(t10, t11, 1, 0x55555555u)
    TRP(t12, t13, 1, 0x55555555u) TRP(t14, t15, 1, 0x55555555u)
    TRP(t16, t17, 1, 0x55555555u) TRP(t18, t19, 1, 0x55555555u)
    TRP(t20, t21, 1, 0x55555555u) TRP(t22, t23, 1, 0x55555555u)
    TRP(t24, t25, 1, 0x55555555u) TRP(t26, t27, 1, 0x55555555u)
    TRP(t28, t29, 1, 0x55555555u) TRP(t30, t31, 1, 0x55555555u)

    // ---- rank-count binary search over bit-planes (MSB -> LSB), DPP sums --
    unsigned T = 0u, E = 0xffffffffu;
    int gcnt = 0;
    SELSTEP(t31, 1u << 31) SELSTEP(t30, 1u << 30) SELSTEP(t29, 1u << 29) SELSTEP(t28, 1u << 28)
    SELSTEP(t27, 1u << 27) SELSTEP(t26, 1u << 26) SELSTEP(t25, 1u << 25) SELSTEP(t24, 1u << 24)
    SELSTEP(t23, 1u << 23) SELSTEP(t22, 1u << 22) SELSTEP(t21, 1u << 21) SELSTEP(t20, 1u << 20)
    SELSTEP(t19, 1u << 19) SELSTEP(t18, 1u << 18) SELSTEP(t17, 1u << 17) SELSTEP(t16, 1u << 16)
    SELSTEP(t15, 1u << 15) SELSTEP(t14, 1u << 14) SELSTEP(t13, 1u << 13) SELSTEP(t12, 1u << 12)
    SELSTEP(t11, 1u << 11) SELSTEP(t10, 1u << 10) SELSTEP(t9, 1u << 9)   SELSTEP(t8, 1u << 8)
    SELSTEP(t7, 1u << 7)   SELSTEP(t6, 1u << 6)   SELSTEP(t5, 1u << 5)   SELSTEP(t4, 1u << 4)
    SELSTEP(t3, 1u << 3)   SELSTEP(t2, 1u << 2)   SELSTEP(t1, 1u << 1)   SELSTEP(t0, 1u)
sel_done: ;
    // threshold = min{u >= T}  (== T when loop completed; tie-exact)
    {
        unsigned mn = 0xffffffffu;
        MNU(u0) MNU(u1) MNU(u2) MNU(u3) MNU(u4) MNU(u5) MNU(u6) MNU(u7)
        MNU(u8) MNU(u9) MNU(u10) MNU(u11) MNU(u12) MNU(u13) MNU(u14) MNU(u15)
        MNU(u16) MNU(u17) MNU(u18) MNU(u19) MNU(u20) MNU(u21) MNU(u22) MNU(u23)
        MNU(u24) MNU(u25) MNU(u26) MNU(u27) MNU(u28) MNU(u29) MNU(u30) MNU(u31)
        T = wmin_dpp(mn);
    }

    // ---- softmax numerators; bf16 P in-place into hi-16 of score words ----
    float lsum = 0.f;
    EXG(u0, u1, u2, u3, 0 * 256)    EXG(u4, u5, u6, u7, 1 * 256)
    EXG(u8, u9, u10, u11, 2 * 256)  EXG(u12, u13, u14, u15, 3 * 256)
    EXG(u16, u17, u18, u19, 4 * 256) EXG(u20, u21, u22, u23, 5 * 256)
    EXG(u24, u25, u26, u27, 6 * 256) EXG(u28, u29, u30, u31, 7 * 256)
    return 1.f / fsum_dpp(lsum);
}

// ---------------------------------------------------------------------------
// Fused attention R18 — R13 geometry (16 waves, 1 block/CU), DPP reductions.
// Single variable vs R13's 565us.
// ---------------------------------------------------------------------------
__global__ __launch_bounds__(1024, 4)
void attn_kernel(const unsigned short* __restrict__ Qh, const unsigned short* __restrict__ Ql,
                 const unsigned short* __restrict__ Kh, const unsigned short* __restrict__ Kl,
                 const unsigned short* __restrict__ Vt,
                 unsigned short* __restrict__ AOh, unsigned short* __restrict__ AOl)
{
    extern __shared__ __align__(16) char smem[];
    unsigned* S = (unsigned*)smem;          // [16][SSTR] ord scores / bf16-P overlay
    float* Opart = (float*)smem;            // overlay [16][16][64] after PV reads done

    const int tid  = threadIdx.x;
    const int lane = tid & 63;
    const int w    = tid >> 6;              // 0..15
    const int q15  = lane & 15;
    const int quad = lane >> 4;

    // XCD swizzle: 4 heads per XCD -> K+V working set ~3 MB, fits 4 MB L2
    const int blk = blockIdx.x;
    const int bh  = (blk & 7) * 4 + ((blk >> 3) & 3);
    const int q0  = (blk >> 5) * 16;

    // ---- Q B-frags direct from global ----
    const size_t qrow = ((size_t)bh * S_LEN + q0 + q15) * HDIM;
    const bf16x8 bqh0 = *(const bf16x8*)(Qh + qrow + quad * 8);
    const bf16x8 bqh1 = *(const bf16x8*)(Qh + qrow + 32 + quad * 8);
    const bf16x8 bql0 = *(const bf16x8*)(Ql + qrow + quad * 8);
    const bf16x8 bql1 = *(const bf16x8*)(Ql + qrow + 32 + quad * 8);

    const size_t kbase = (size_t)bh * S_LEN * HDIM;

    // ---- phase 1: QK^T, 8 key-tiles per wave, straight to LDS ----
#pragma unroll 4
    for (int t = 0; t < 8; ++t) {
        const int key = w * 128 + t * 16 + q15;     // A-frag m
        const unsigned short* kh = Kh + kbase + (size_t)key * HDIM + quad * 8;
        const unsigned short* kl = Kl + kbase + (size_t)key * HDIM + quad * 8;
        const bf16x8 akh0 = *(const bf16x8*)(kh);
        const bf16x8 akh1 = *(const bf16x8*)(kh + 32);
        const bf16x8 akl0 = *(const bf16x8*)(kl);
        const bf16x8 akl1 = *(const bf16x8*)(kl + 32);
        f32x4 c = {0.f, 0.f, 0.f, 0.f};
        c = __builtin_amdgcn_mfma_f32_16x16x32_bf16(akh0, bqh0, c, 0, 0, 0);
        c = __builtin_amdgcn_mfma_f32_16x16x32_bf16(akh1, bqh1, c, 0, 0, 0);
        c = __builtin_amdgcn_mfma_f32_16x16x32_bf16(akh0, bql0, c, 0, 0, 0);
        c = __builtin_amdgcn_mfma_f32_16x16x32_bf16(akh1, bql1, c, 0, 0, 0);
        c = __builtin_amdgcn_mfma_f32_16x16x32_bf16(akl0, bqh0, c, 0, 0, 0);
        c = __builtin_amdgcn_mfma_f32_16x16x32_bf16(akl1, bqh1, c, 0, 0, 0);
        c = c * 0.125f;
        // C-layout: col=lane&15=q(row of S), row-in-tile=quad*4+reg=key(col)
        uint4 o;
        o.x = f2ord(c[0]); o.y = f2ord(c[1]); o.z = f2ord(c[2]); o.w = f2ord(c[3]);
        *(uint4*)(S + q15 * SSTR + w * 128 + t * 16 + quad * 4) = o;
    }
    __syncthreads();   // full [16][2048] score matrix visible

    // ---- phase 2: one row per wave: select + softmax, in-place bf16 P ----
    const float invd = row_pass(S + w * SSTR, lane);
    __syncthreads();   // all P visible

    // ---- phase 3: dense PV via bf16 MFMA, wave w keys [128w,128w+128) ----
    {
        f32x4 oacc[4];
#pragma unroll
        for (int ht = 0; ht < 4; ++ht) oacc[ht] = (f32x4){0.f, 0.f, 0.f, 0.f};
        const size_t vtb = (size_t)bh * HDIM * S_LEN;
        const unsigned* Srow = S + q15 * SSTR;
#pragma unroll 2
        for (int ks = 0; ks < 4; ++ks) {
            const int key0 = w * 128 + ks * 32 + quad * 8;
            const uint4 a0 = *(const uint4*)(Srow + key0);
            const uint4 a1 = *(const uint4*)(Srow + key0 + 4);
            const bf16x8 ap = pack_hi8(a0, a1);                      // A[m=q][k=key]
#pragma unroll
            for (int ht = 0; ht < 4; ++ht) {
                const int hd = ht * 16 + q15;                        // B[k=key][n=hd]
                const bf16x8 bv = *(const bf16x8*)(Vt + vtb + (size_t)hd * S_LEN + key0);
                oacc[ht] = __builtin_amdgcn_mfma_f32_16x16x32_bf16(ap, bv, oacc[ht], 0, 0, 0);
            }
        }
        __syncthreads();   // all P reads done; score region dead -> Opart live
        // D[m=q][n=hd]: col=lane&15=hd-in-tile, row=quad*4+reg=q
#pragma unroll
        for (int ht = 0; ht < 4; ++ht)
#pragma unroll
            for (int rg = 0; rg < 4; ++rg)
                Opart[w * 1024 + (quad * 4 + rg) * 64 + ht * 16 + q15] = oacc[ht][rg];
    }
    __syncthreads();

    // ---- final: wave w reduces 16 partials for row w, writes AO hi/lo ----
    {
        float s = 0.f;
#pragma unroll
        for (int ww = 0; ww < 16; ++ww)
            s += Opart[ww * 1024 + w * 64 + lane];
        const int b = bh >> 4, h = bh & 15;
        const float o = s * invd;
        const size_t i = ((size_t)(b * S_LEN + q0 + w)) * DMODEL + h * HDIM + lane;
        const unsigned short oh = f2bf(o);
        AOh[i] = oh; AOl[i] = f2bf(o - bf2f(oh));
    }
}

// ---------------------------------------------------------------------------
extern "C" void kernel_launch(void* const* d_in, const int* in_sizes, int n_in,
                              void* d_out, int out_size, void* d_ws, size_t ws_size,
                              hipStream_t stream)
{
    const float* X  = (const float*)d_in[0];
    const float* Wq = (const float*)d_in[1];
    const float* bq = (const float*)d_in[2];
    const float* Wk = (const float*)d_in[3];
    const float* bk = (const float*)d_in[4];
    const float* Wv = (const float*)d_in[5];
    const float* bv = (const float*)d_in[6];
    const float* Wo = (const float*)d_in[7];
    const float* bo = (const float*)d_in[8];

    char* p = (char*)d_ws;
    const size_t NEL = (size_t)BHC * S_LEN * HDIM;   // 4,194,304
    unsigned short* Q16h = (unsigned short*)p; p += NEL * 2;
    unsigned short* Q16l = (unsigned short*)p; p += NEL * 2;
    unsigned short* K16h = (unsigned short*)p; p += NEL * 2;
    unsigned short* K16l = (unsigned short*)p; p += NEL * 2;
    unsigned short* Vb16 = (unsigned short*)p; p += NEL * 2;
    unsigned short* Vt16 = (unsigned short*)p; p += NEL * 2;
    unsigned short* Xh   = (unsigned short*)p; p += NEL * 2;
    unsigned short* Xl   = (unsigned short*)p; p += NEL * 2;
    unsigned short* AOh  = (unsigned short*)p; p += NEL * 2;
    unsigned short* AOl  = (unsigned short*)p; p += NEL * 2;
    unsigned short* Wqh  = (unsigned short*)p; p += DMODEL * DMODEL * 2;
    unsigned short* Wql  = (unsigned short*)p; p += DMODEL * DMODEL * 2;
    unsigned short* Wkh  = (unsigned short*)p; p += DMODEL * DMODEL * 2;
    unsigned short* Wkl  = (unsigned short*)p; p += DMODEL * DMODEL * 2;
    unsigned short* Wvh  = (unsigned short*)p; p += DMODEL * DMODEL * 2;
    unsigned short* Wvl  = (unsigned short*)p; p += DMODEL * DMODEL * 2;
    unsigned short* Woh  = (unsigned short*)p; p += DMODEL * DMODEL * 2;
    unsigned short* Wol  = (unsigned short*)p; p += DMODEL * DMODEL * 2;

    const int attn_lds = 16 * SSTR * 4;   // 131,328 B -> 1 block/CU
    hipFuncSetAttribute((const void*)attn_kernel,
                        hipFuncAttributeMaxDynamicSharedMemorySize, attn_lds);

    const int X4 = (int)(NEL / 4);
    const int W4 = DMODEL * DMODEL / 4;

    // ---- input splits ----
    split32<<<(X4 + 255) / 256, 256, 0, stream>>>(X,  Xh,  Xl,  X4);
    split32<<<(W4 + 255) / 256, 256, 0, stream>>>(Wq, Wqh, Wql, W4);
    split32<<<(W4 + 255) / 256, 256, 0, stream>>>(Wk, Wkh, Wkl, W4);
    split32<<<(W4 + 255) / 256, 256, 0, stream>>>(Wv, Wvh, Wvl, W4);
    split32<<<(W4 + 255) / 256, 256, 0, stream>>>(Wo, Woh, Wol, W4);

    // ---- projections ----
    const dim3 ggrid(16, 32, 1);
    gemm_mfma<<<ggrid, 256, 0, stream>>>(Xh, Xl, Wqh, Wql, bq, Q16h, Q16l, 2);
    gemm_mfma<<<ggrid, 256, 0, stream>>>(Xh, Xl, Wkh, Wkl, bk, K16h, K16l, 2);
    gemm_mfma<<<ggrid, 256, 0, stream>>>(Xh, Xl, Wvh, Wvl, bv, Vb16, nullptr, 3);
    transpose_v16<<<dim3(32, 32, 1), 256, 0, stream>>>(Vb16, Vt16);

    // ---- fused attention (R18: DPP wave reductions) ----
    attn_kernel<<<4096, 1024, attn_lds, stream>>>(Q16h, Q16l, K16h, K16l, Vt16, AOh, AOl);

    // ---- output projection ----
    gemm_mfma<<<ggrid, 256, 0, stream>>>(AOh, AOl, Woh, Wol, bo, d_out, nullptr, 0);
}

// Round 18
// 752.034 us; speedup vs baseline: 2.3041x; 1.0132x over previous
//
#include <hip/hip_runtime.h>
#include <math.h>

#define S_LEN 2048
#define NH 16
#define HDIM 64
#define BATCH 2
#define BHC 32          // BATCH*NH
#define KK 409          // int(2048 * (1.0 - 0.8)) per reference float math
#define DMODEL 1024

typedef __attribute__((ext_vector_type(8))) short bf16x8;   // 8 bf16 in 4 VGPRs
typedef __attribute__((ext_vector_type(4))) float f32x4;

// LDS-resident score matrix. 16 rows * 2052 * 4 B = 131,328 B -> 1 block/CU.
// 2052 % 32 == 4 -> no hot bank on any access pattern below.
#define SSTR 2052
#define T_STR  40       // bf16 LDS tile row stride for gemm: 80 B, 16B-aligned

__device__ __forceinline__ unsigned f2ord(float f) {
    unsigned u = __float_as_uint(f);
    return (u & 0x80000000u) ? ~u : (u | 0x80000000u);
}
__device__ __forceinline__ float ord2f(unsigned v) {
    unsigned u = (v & 0x80000000u) ? (v & 0x7fffffffu) : ~v;
    return __uint_as_float(u);
}
__device__ __forceinline__ unsigned short f2bf(float f) {   // RNE
    unsigned u = __float_as_uint(f);
    u += 0x7fffu + ((u >> 16) & 1u);
    return (unsigned short)(u >> 16);
}
__device__ __forceinline__ float bf2f(unsigned short h) {
    return __uint_as_float(((unsigned)h) << 16);
}

// ---------------------------------------------------------------------------
// DPP wave64 reductions (rocPRIM recipe) — R18-proven.
// ---------------------------------------------------------------------------
__device__ __forceinline__ int wsum_dpp(int x) {
    x += __builtin_amdgcn_update_dpp(0, x, 0x111, 0xf, 0xf, false);
    x += __builtin_amdgcn_update_dpp(0, x, 0x112, 0xf, 0xf, false);
    x += __builtin_amdgcn_update_dpp(0, x, 0x114, 0xf, 0xe, false);
    x += __builtin_amdgcn_update_dpp(0, x, 0x118, 0xf, 0xc, false);
    x += __builtin_amdgcn_update_dpp(0, x, 0x142, 0xa, 0xf, false);
    x += __builtin_amdgcn_update_dpp(0, x, 0x143, 0xc, 0xf, false);
    return __builtin_amdgcn_readlane(x, 63);
}
__device__ __forceinline__ unsigned wmax_dpp(unsigned x) {
    unsigned t;
    t = (unsigned)__builtin_amdgcn_update_dpp(0, (int)x, 0x111, 0xf, 0xf, false); x = x > t ? x : t;
    t = (unsigned)__builtin_amdgcn_update_dpp(0, (int)x, 0x112, 0xf, 0xf, false); x = x > t ? x : t;
    t = (unsigned)__builtin_amdgcn_update_dpp(0, (int)x, 0x114, 0xf, 0xf, false); x = x > t ? x : t;
    t = (unsigned)__builtin_amdgcn_update_dpp(0, (int)x, 0x118, 0xf, 0xf, false); x = x > t ? x : t;
    t = (unsigned)__builtin_amdgcn_update_dpp(0, (int)x, 0x142, 0xf, 0xf, false); x = x > t ? x : t;
    t = (unsigned)__builtin_amdgcn_update_dpp(0, (int)x, 0x143, 0xf, 0xf, false); x = x > t ? x : t;
    return (unsigned)__builtin_amdgcn_readlane((int)x, 63);
}
__device__ __forceinline__ unsigned wmin_dpp(unsigned x) {
    unsigned t;
    t = (unsigned)__builtin_amdgcn_update_dpp((int)0xffffffff, (int)x, 0x111, 0xf, 0xf, false); x = x < t ? x : t;
    t = (unsigned)__builtin_amdgcn_update_dpp((int)0xffffffff, (int)x, 0x112, 0xf, 0xf, false); x = x < t ? x : t;
    t = (unsigned)__builtin_amdgcn_update_dpp((int)0xffffffff, (int)x, 0x114, 0xf, 0xf, false); x = x < t ? x : t;
    t = (unsigned)__builtin_amdgcn_update_dpp((int)0xffffffff, (int)x, 0x118, 0xf, 0xf, false); x = x < t ? x : t;
    t = (unsigned)__builtin_amdgcn_update_dpp((int)0xffffffff, (int)x, 0x142, 0xf, 0xf, false); x = x < t ? x : t;
    t = (unsigned)__builtin_amdgcn_update_dpp((int)0xffffffff, (int)x, 0x143, 0xf, 0xf, false); x = x < t ? x : t;
    return (unsigned)__builtin_amdgcn_readlane((int)x, 63);
}
__device__ __forceinline__ float fsum_dpp(float x) {
    x += __int_as_float(__builtin_amdgcn_update_dpp(0, __float_as_int(x), 0x111, 0xf, 0xf, false));
    x += __int_as_float(__builtin_amdgcn_update_dpp(0, __float_as_int(x), 0x112, 0xf, 0xf, false));
    x += __int_as_float(__builtin_amdgcn_update_dpp(0, __float_as_int(x), 0x114, 0xf, 0xe, false));
    x += __int_as_float(__builtin_amdgcn_update_dpp(0, __float_as_int(x), 0x118, 0xf, 0xc, false));
    x += __int_as_float(__builtin_amdgcn_update_dpp(0, __float_as_int(x), 0x142, 0xa, 0xf, false));
    x += __int_as_float(__builtin_amdgcn_update_dpp(0, __float_as_int(x), 0x143, 0xc, 0xf, false));
    return __int_as_float(__builtin_amdgcn_readlane(__float_as_int(x), 63));
}

// ---------------------------------------------------------------------------
// fp32 -> bf16 hi/lo split (vectorized float4 / ushort4), n4 = elements/4
// ---------------------------------------------------------------------------
__global__ __launch_bounds__(256)
void split32(const float* __restrict__ in, unsigned short* __restrict__ hi,
             unsigned short* __restrict__ lo, int n4)
{
    const int i = blockIdx.x * 256 + threadIdx.x;
    if (i < n4) {
        const float4 v = ((const float4*)in)[i];
        ushort4 h, l;
        h.x = f2bf(v.x); l.x = f2bf(v.x - bf2f(h.x));
        h.y = f2bf(v.y); l.y = f2bf(v.y - bf2f(h.y));
        h.z = f2bf(v.z); l.z = f2bf(v.z - bf2f(h.z));
        h.w = f2bf(v.w); l.w = f2bf(v.w - bf2f(h.w));
        ((ushort4*)hi)[i] = h;
        ((ushort4*)lo)[i] = l;
    }
}

// ---------------------------------------------------------------------------
// LDS-staged split-bf16 3-pass MFMA GEMM (unchanged — R8 banked structure).
// ---------------------------------------------------------------------------
__global__ __launch_bounds__(256)
void gemm_mfma(const unsigned short* __restrict__ Ah, const unsigned short* __restrict__ Al,
               const unsigned short* __restrict__ Bh, const unsigned short* __restrict__ Bl,
               const float* __restrict__ bias, void* __restrict__ out0,
               void* __restrict__ out1, int mode)
{
    __shared__ __align__(16) unsigned short sAh[128 * T_STR];
    __shared__ __align__(16) unsigned short sAl[128 * T_STR];
    __shared__ __align__(16) unsigned short sBh[64 * T_STR];
    __shared__ __align__(16) unsigned short sBl[64 * T_STR];

    const int tid  = threadIdx.x;
    const int lane = tid & 63;
    const int w    = tid >> 6;
    const int q15  = lane & 15;
    const int quad = lane >> 4;
    const int n0b = blockIdx.x * 64;
    const int m0b = blockIdx.y * 128;
    const int wm = (w >> 1) * 64;
    const int wn = (w & 1) * 32;

    const int ar0 = tid >> 2, aks0 = (tid & 3) * 8;
    const int ar1 = (tid + 256) >> 2, aks1 = aks0;
    const int br = tid >> 2, bks = (tid & 3) * 8;

    const unsigned short* gAh0 = Ah + (size_t)(m0b + ar0) * 1024 + aks0;
    const unsigned short* gAh1 = Ah + (size_t)(m0b + ar1) * 1024 + aks1;
    const unsigned short* gAl0 = Al + (size_t)(m0b + ar0) * 1024 + aks0;
    const unsigned short* gAl1 = Al + (size_t)(m0b + ar1) * 1024 + aks1;
    const unsigned short* gBh = Bh + (size_t)(n0b + br) * 1024 + bks;
    const unsigned short* gBl = Bl + (size_t)(n0b + br) * 1024 + bks;

    f32x4 acc[4][2];
#pragma unroll
    for (int mt = 0; mt < 4; ++mt)
#pragma unroll
        for (int nt = 0; nt < 2; ++nt) acc[mt][nt] = (f32x4){0.f, 0.f, 0.f, 0.f};

#pragma unroll 1
    for (int k0 = 0; k0 < 1024; k0 += 32) {
        const bf16x8 vah0 = *(const bf16x8*)(gAh0 + k0);
        const bf16x8 vah1 = *(const bf16x8*)(gAh1 + k0);
        const bf16x8 val0 = *(const bf16x8*)(gAl0 + k0);
        const bf16x8 val1 = *(const bf16x8*)(gAl1 + k0);
        const bf16x8 vbh  = *(const bf16x8*)(gBh + k0);
        const bf16x8 vbl  = *(const bf16x8*)(gBl + k0);
        __syncthreads();
        *(bf16x8*)(sAh + ar0 * T_STR + aks0) = vah0;
        *(bf16x8*)(sAh + ar1 * T_STR + aks1) = vah1;
        *(bf16x8*)(sAl + ar0 * T_STR + aks0) = val0;
        *(bf16x8*)(sAl + ar1 * T_STR + aks1) = val1;
        *(bf16x8*)(sBh + br * T_STR + bks) = vbh;
        *(bf16x8*)(sBl + br * T_STR + bks) = vbl;
        __syncthreads();

        bf16x8 fbh[2], fbl[2];
#pragma unroll
        for (int nt = 0; nt < 2; ++nt) {
            fbh[nt] = *(const bf16x8*)(sBh + (wn + nt * 16 + q15) * T_STR + quad * 8);
            fbl[nt] = *(const bf16x8*)(sBl + (wn + nt * 16 + q15) * T_STR + quad * 8);
        }
#pragma unroll
        for (int mt = 0; mt < 4; ++mt) {
            const bf16x8 fah = *(const bf16x8*)(sAh + (wm + mt * 16 + q15) * T_STR + quad * 8);
            const bf16x8 fal = *(const bf16x8*)(sAl + (wm + mt * 16 + q15) * T_STR + quad * 8);
#pragma unroll
            for (int nt = 0; nt < 2; ++nt) {
                acc[mt][nt] = __builtin_amdgcn_mfma_f32_16x16x32_bf16(fah, fbh[nt], acc[mt][nt], 0, 0, 0);
                acc[mt][nt] = __builtin_amdgcn_mfma_f32_16x16x32_bf16(fah, fbl[nt], acc[mt][nt], 0, 0, 0);
                acc[mt][nt] = __builtin_amdgcn_mfma_f32_16x16x32_bf16(fal, fbh[nt], acc[mt][nt], 0, 0, 0);
            }
        }
    }

#pragma unroll
    for (int nt = 0; nt < 2; ++nt) {
        const int n = n0b + wn + nt * 16 + q15;
        const float bv = bias[n];
#pragma unroll
        for (int mt = 0; mt < 4; ++mt) {
            const int mb = m0b + wm + mt * 16 + quad * 4;
#pragma unroll
            for (int rg = 0; rg < 4; ++rg) {
                const int m = mb + rg;
                const float o = acc[mt][nt][rg] + bv;
                if (mode == 0) {
                    ((float*)out0)[(size_t)m * 1024 + n] = o;
                } else {
                    const int b = m >> 11, s = m & 2047;
                    const int h = n >> 6, hd = n & 63;
                    const size_t base = ((size_t)((b * NH + h) * S_LEN + s)) * HDIM + hd;
                    if (mode == 3) {
                        ((unsigned short*)out0)[base] = f2bf(o);
                    } else {
                        const unsigned short oh = f2bf(o);
                        ((unsigned short*)out0)[base] = oh;
                        ((unsigned short*)out1)[base] = f2bf(o - bf2f(oh));
                    }
                }
            }
        }
    }
}

// ---------------------------------------------------------------------------
// V bf16 [bh][s][64] -> Vt bf16 [bh][64][2048]
// ---------------------------------------------------------------------------
__global__ __launch_bounds__(256)
void transpose_v16(const unsigned short* __restrict__ V, unsigned short* __restrict__ Vt)
{
    __shared__ unsigned short t[64][72];
    const int tid = threadIdx.x;
    const int s0 = blockIdx.x * 64;
    const int bh = blockIdx.y;
    const unsigned short* Vb = V + (size_t)bh * S_LEN * HDIM;
#pragma unroll
    for (int i = 0; i < 4; ++i) {
        const int f = tid + i * 256;
        const int s = f >> 4;
        const int hq = (f & 15) * 4;
        const ushort4 v = *(const ushort4*)(Vb + (size_t)(s0 + s) * HDIM + hq);
        t[s][hq + 0] = v.x; t[s][hq + 1] = v.y; t[s][hq + 2] = v.z; t[s][hq + 3] = v.w;
    }
    __syncthreads();
    unsigned short* Vtb = Vt + (size_t)bh * HDIM * S_LEN;
#pragma unroll
    for (int i = 0; i < 4; ++i) {
        const int f = tid + i * 256;
        const int hd = f >> 4;
        const int sq = (f & 15) * 4;
        ushort4 v;
        v.x = t[sq + 0][hd]; v.y = t[sq + 1][hd];
        v.z = t[sq + 2][hd]; v.w = t[sq + 3][hd];
        *(ushort4*)(Vtb + (size_t)hd * S_LEN + s0 + sq) = v;
    }
}

__device__ __forceinline__ bf16x8 pack_hi8(const uint4 a0, const uint4 a1)
{
    union { unsigned u[4]; bf16x8 v; } c;
    c.u[0] = (a0.x >> 16) | (a0.y & 0xffff0000u);
    c.u[1] = (a0.z >> 16) | (a0.w & 0xffff0000u);
    c.u[2] = (a1.x >> 16) | (a1.y & 0xffff0000u);
    c.u[3] = (a1.z >> 16) | (a1.w & 0xffff0000u);
    return c.v;
}

// ---------------------------------------------------------------------------
// Phase-2 row pass — R18-proven: 1-bit rank-count select with DPP reductions.
// ---------------------------------------------------------------------------
#define TRP(AK, AKJ, J, M) { const unsigned _t = (((AK) >> (J)) ^ (AKJ)) & (M); \
                             (AK) ^= _t << (J); (AKJ) ^= _t; }
#define UMX(A, B) ((A) > (B) ? (A) : (B))

#define SELSTEP(TB, BITV) { \
    const unsigned eb = E & (TB); \
    const int cnt = gcnt + wsum_dpp(__builtin_popcount(eb)); \
    if (cnt >= KK) { T |= (BITV); E = eb; if (cnt == KK) goto sel_done; } \
    else { gcnt = cnt; E &= ~(TB); } \
}

#define MNU(U) { const unsigned _v = (U) >= T ? (U) : 0xffffffffu; mn = _v < mn ? _v : mn; }

#define EXG(UA, UB, UC, UD, OFF) { \
    const float ea = (UA) >= T ? __expf(ord2f(UA) - mx) : 0.f; \
    const float eb_ = (UB) >= T ? __expf(ord2f(UB) - mx) : 0.f; \
    const float ec = (UC) >= T ? __expf(ord2f(UC) - mx) : 0.f; \
    const float ed = (UD) >= T ? __expf(ord2f(UD) - mx) : 0.f; \
    uint4 wv; \
    wv.x = ((unsigned)f2bf(ea)) << 16; \
    wv.y = ((unsigned)f2bf(eb_)) << 16; \
    wv.z = ((unsigned)f2bf(ec)) << 16; \
    wv.w = ((unsigned)f2bf(ed)) << 16; \
    *(uint4*)(R + (OFF) + lane * 4) = wv; \
    lsum += ea + eb_ + ec + ed; }

__device__ __forceinline__ float row_pass(unsigned* R, const int lane)
{
    const uint4 q0 = *(const uint4*)(R + 0 * 256 + lane * 4);
    const uint4 q1 = *(const uint4*)(R + 1 * 256 + lane * 4);
    const uint4 q2 = *(const uint4*)(R + 2 * 256 + lane * 4);
    const uint4 q3 = *(const uint4*)(R + 3 * 256 + lane * 4);
    const uint4 q4 = *(const uint4*)(R + 4 * 256 + lane * 4);
    const uint4 q5 = *(const uint4*)(R + 5 * 256 + lane * 4);
    const uint4 q6 = *(const uint4*)(R + 6 * 256 + lane * 4);
    const uint4 q7 = *(const uint4*)(R + 7 * 256 + lane * 4);
    const unsigned u0  = q0.x, u1  = q0.y, u2  = q0.z, u3  = q0.w;
    const unsigned u4  = q1.x, u5  = q1.y, u6  = q1.z, u7  = q1.w;
    const unsigned u8  = q2.x, u9  = q2.y, u10 = q2.z, u11 = q2.w;
    const unsigned u12 = q3.x, u13 = q3.y, u14 = q3.z, u15 = q3.w;
    const unsigned u16 = q4.x, u17 = q4.y, u18 = q4.z, u19 = q4.w;
    const unsigned u20 = q5.x, u21 = q5.y, u22 = q5.z, u23 = q5.w;
    const unsigned u24 = q6.x, u25 = q6.y, u26 = q6.z, u27 = q6.w;
    const unsigned u28 = q7.x, u29 = q7.y, u30 = q7.z, u31 = q7.w;

    const unsigned a0 = UMX(u0, u1),  a1 = UMX(u2, u3),  a2 = UMX(u4, u5),  a3 = UMX(u6, u7);
    const unsigned a4 = UMX(u8, u9),  a5 = UMX(u10, u11), a6 = UMX(u12, u13), a7 = UMX(u14, u15);
    const unsigned a8 = UMX(u16, u17), a9 = UMX(u18, u19), a10 = UMX(u20, u21), a11 = UMX(u22, u23);
    const unsigned a12 = UMX(u24, u25), a13 = UMX(u26, u27), a14 = UMX(u28, u29), a15 = UMX(u30, u31);
    const unsigned b0 = UMX(a0, a1), b1 = UMX(a2, a3), b2 = UMX(a4, a5), b3 = UMX(a6, a7);
    const unsigned b4 = UMX(a8, a9), b5 = UMX(a10, a11), b6 = UMX(a12, a13), b7 = UMX(a14, a15);
    const unsigned c0 = UMX(b0, b1), c1 = UMX(b2, b3), c2 = UMX(b4, b5), c3 = UMX(b6, b7);
    const unsigned umx = wmax_dpp(UMX(UMX(c0, c1), UMX(c2, c3)));
    const float mx = ord2f(umx);

    unsigned t0 = u0,  t1 = u1,  t2 = u2,  t3 = u3,  t4 = u4,  t5 = u5,  t6 = u6,  t7 = u7;
    unsigned t8 = u8,  t9 = u9,  t10 = u10, t11 = u11, t12 = u12, t13 = u13, t14 = u14, t15 = u15;
    unsigned t16 = u16, t17 = u17, t18 = u18, t19 = u19, t20 = u20, t21 = u21, t22 = u22, t23 = u23;
    unsigned t24 = u24, t25 = u25, t26 = u26, t27 = u27, t28 = u28, t29 = u29, t30 = u30, t31 = u31;
    TRP(t0, t16, 16, 0x0000FFFFu) TRP(t1, t17, 16, 0x0000FFFFu)
    TRP(t2, t18, 16, 0x0000FFFFu) TRP(t3, t19, 16, 0x0000FFFFu)
    TRP(t4, t20, 16, 0x0000FFFFu) TRP(t5, t21, 16, 0x0000FFFFu)
    TRP(t6, t22, 16, 0x0000FFFFu) TRP(t7, t23, 16, 0x0000FFFFu)
    TRP(t8, t24, 16, 0x0000FFFFu) TRP(t9, t25, 16, 0x0000FFFFu)
    TRP(t10, t26, 16, 0x0000FFFFu) TRP(t11, t27, 16, 0x0000FFFFu)
    TRP(t12, t28, 16, 0x0000FFFFu) TRP(t13, t29, 16, 0x0000FFFFu)
    TRP(t14, t30, 16, 0x0000FFFFu) TRP(t15, t31, 16, 0x0000FFFFu)
    TRP(t0, t8, 8, 0x00FF00FFu)  TRP(t1, t9, 8, 0x00FF00FFu)
    TRP(t2, t10, 8, 0x00FF00FFu) TRP(t3, t11, 8, 0x00FF00FFu)
    TRP(t4, t12, 8, 0x00FF00FFu) TRP(t5, t13, 8, 0x00FF00FFu)
    TRP(t6, t14, 8, 0x00FF00FFu) TRP(t7, t15, 8, 0x00FF00FFu)
    TRP(t16, t24, 8, 0x00FF00FFu) TRP(t17, t25, 8, 0x00FF00FFu)
    TRP(t18, t26, 8, 0x00FF00FFu) TRP(t19, t27, 8, 0x00FF00FFu)
    TRP(t20, t28, 8, 0x00FF00FFu) TRP(t21, t29, 8, 0x00FF00FFu)
    TRP(t22, t30, 8, 0x00FF00FFu) TRP(t23, t31, 8, 0x00FF00FFu)
    TRP(t0, t4, 4, 0x0F0F0F0Fu)  TRP(t1, t5, 4, 0x0F0F0F0Fu)
    TRP(t2, t6, 4, 0x0F0F0F0Fu)  TRP(t3, t7, 4, 0x0F0F0F0Fu)
    TRP(t8, t12, 4, 0x0F0F0F0Fu) TRP(t9, t13, 4, 0x0F0F0F0Fu)
    TRP(t10, t14, 4, 0x0F0F0F0Fu) TRP(t11, t15, 4, 0x0F0F0F0Fu)
    TRP(t16, t20, 4, 0x0F0F0F0Fu) TRP(t17, t21, 4, 0x0F0F0F0Fu)
    TRP(t18, t22, 4, 0x0F0F0F0Fu) TRP(t19, t23, 4, 0x0F0F0F0Fu)
    TRP(t24, t28, 4, 0x0F0F0F0Fu) TRP(t25, t29, 4, 0x0F0F0F0Fu)
    TRP(t26, t30, 4, 0x0F0F0F0Fu) TRP(t27, t31, 4, 0x0F0F0F0Fu)
    TRP(t0, t2, 2, 0x33333333u)  TRP(t1, t3, 2, 0x33333333u)
    TRP(t4, t6, 2, 0x33333333u)  TRP(t5, t7, 2, 0x33333333u)
    TRP(t8, t10, 2, 0x33333333u) TRP(t9, t11, 2, 0x33333333u)
    TRP(t12, t14, 2, 0x33333333u) TRP(t13, t15, 2, 0x33333333u)
    TRP(t16, t18, 2, 0x33333333u) TRP(t17, t19, 2, 0x33333333u)
    TRP(t20, t22, 2, 0x33333333u) TRP(t21, t23, 2, 0x33333333u)
    TRP(t24, t26, 2, 0x33333333u) TRP(t25, t27, 2, 0x33333333u)
    TRP(t28, t30, 2, 0x33333333u) TRP(t29, t31, 2, 0x33333333u)
    TRP(t0, t1, 1, 0x55555555u)  TRP(t2, t3, 1, 0x55555555u)
    TRP(t4, t5, 1, 0x55555555u)  TRP(t6, t7, 1, 0x55555555u)
    TRP(t8, t9, 1, 0x55555555u)  TRP(t10, t11, 1, 0x55555555u)
    TRP(t12, t13, 1, 0x55555555u) TRP(t14, t15, 1, 0x55555555u)
    TRP(t16, t17, 1, 0x55555555u) TRP(t18, t19, 1, 0x55555555u)
    TRP(t20, t21, 1, 0x55555555u) TRP(t22, t23, 1, 0x55555555u)
    TRP(t24, t25, 1, 0x55555555u) TRP(t26, t27, 1, 0x55555555u)
    TRP(t28, t29, 1, 0x55555555u) TRP(t30, t31, 1, 0x55555555u)

    unsigned T = 0u, E = 0xffffffffu;
    int gcnt = 0;
    SELSTEP(t31, 1u << 31) SELSTEP(t30, 1u << 30) SELSTEP(t29, 1u << 29) SELSTEP(t28, 1u << 28)
    SELSTEP(t27, 1u << 27) SELSTEP(t26, 1u << 26) SELSTEP(t25, 1u << 25) SELSTEP(t24, 1u << 24)
    SELSTEP(t23, 1u << 23) SELSTEP(t22, 1u << 22) SELSTEP(t21, 1u << 21) SELSTEP(t20, 1u << 20)
    SELSTEP(t19, 1u << 19) SELSTEP(t18, 1u << 18) SELSTEP(t17, 1u << 17) SELSTEP(t16, 1u << 16)
    SELSTEP(t15, 1u << 15) SELSTEP(t14, 1u << 14) SELSTEP(t13, 1u << 13) SELSTEP(t12, 1u << 12)
    SELSTEP(t11, 1u << 11) SELSTEP(t10, 1u << 10) SELSTEP(t9, 1u << 9)   SELSTEP(t8, 1u << 8)
    SELSTEP(t7, 1u << 7)   SELSTEP(t6, 1u << 6)   SELSTEP(t5, 1u << 5)   SELSTEP(t4, 1u << 4)
    SELSTEP(t3, 1u << 3)   SELSTEP(t2, 1u << 2)   SELSTEP(t1, 1u << 1)   SELSTEP(t0, 1u)
sel_done: ;
    {
        unsigned mn = 0xffffffffu;
        MNU(u0) MNU(u1) MNU(u2) MNU(u3) MNU(u4) MNU(u5) MNU(u6) MNU(u7)
        MNU(u8) MNU(u9) MNU(u10) MNU(u11) MNU(u12) MNU(u13) MNU(u14) MNU(u15)
        MNU(u16) MNU(u17) MNU(u18) MNU(u19) MNU(u20) MNU(u21) MNU(u22) MNU(u23)
        MNU(u24) MNU(u25) MNU(u26) MNU(u27) MNU(u28) MNU(u29) MNU(u30) MNU(u31)
        T = wmin_dpp(mn);
    }

    float lsum = 0.f;
    EXG(u0, u1, u2, u3, 0 * 256)    EXG(u4, u5, u6, u7, 1 * 256)
    EXG(u8, u9, u10, u11, 2 * 256)  EXG(u12, u13, u14, u15, 3 * 256)
    EXG(u16, u17, u18, u19, 4 * 256) EXG(u20, u21, u22, u23, 5 * 256)
    EXG(u24, u25, u26, u27, 6 * 256) EXG(u28, u29, u30, u31, 7 * 256)
    return 1.f / fsum_dpp(lsum);
}

// ---------------------------------------------------------------------------
// Fused attention R19 — R18 numerics + deep register prefetch in QK^T / PV.
// (R18 post-mortem: select fully optimized (DPP); remaining wall is q+p
//  ~260us at ~3x the L2-BW floor.  VGPR_Count=56 of a 128 budget proves the
//  compiler keeps only ~4-8 loads in flight -> per-tile ~300cyc L2 latency
//  exposed.  Fix: preload ALL 16 K-hi frags + rolling 2-tile K-lo window
//  before MFMAs; PV hoists all 16 V loads + 8 P-LDS reads.  Named scalars
//  only (rule #20); per-tile MFMA accumulation order preserved.)
// ---------------------------------------------------------------------------
__global__ __launch_bounds__(1024, 4)
void attn_kernel(const unsigned short* __restrict__ Qh, const unsigned short* __restrict__ Ql,
                 const unsigned short* __restrict__ Kh, const unsigned short* __restrict__ Kl,
                 const unsigned short* __restrict__ Vt,
                 unsigned short* __restrict__ AOh, unsigned short* __restrict__ AOl)
{
    extern __shared__ __align__(16) char smem[];
    unsigned* S = (unsigned*)smem;          // [16][SSTR] ord scores / bf16-P overlay
    float* Opart = (float*)smem;            // overlay [16][16][64] after PV reads done

    const int tid  = threadIdx.x;
    const int lane = tid & 63;
    const int w    = tid >> 6;              // 0..15
    const int q15  = lane & 15;
    const int quad = lane >> 4;

    // XCD swizzle: 4 heads per XCD -> K+V working set ~3 MB, fits 4 MB L2
    const int blk = blockIdx.x;
    const int bh  = (blk & 7) * 4 + ((blk >> 3) & 3);
    const int q0  = (blk >> 5) * 16;

    // ---- Q B-frags direct from global ----
    const size_t qrow = ((size_t)bh * S_LEN + q0 + q15) * HDIM;
    const bf16x8 bqh0 = *(const bf16x8*)(Qh + qrow + quad * 8);
    const bf16x8 bqh1 = *(const bf16x8*)(Qh + qrow + 32 + quad * 8);
    const bf16x8 bql0 = *(const bf16x8*)(Ql + qrow + quad * 8);
    const bf16x8 bql1 = *(const bf16x8*)(Ql + qrow + 32 + quad * 8);

    const size_t kbase = (size_t)bh * S_LEN * HDIM;

    // ---- phase 1: QK^T, 8 tiles/wave; ALL kh preloaded, rolling kl ----
    {
        const unsigned short* kb = Kh + kbase + (size_t)(w * 128 + q15) * HDIM + quad * 8;
        const unsigned short* lb = Kl + kbase + (size_t)(w * 128 + q15) * HDIM + quad * 8;
        // tile stride = 16 rows * HDIM = 1024 elements
#define LDT(P, T, O) (*(const bf16x8*)((P) + (T) * 1024 + (O)))
        const bf16x8 h0a = LDT(kb,0,0), h0b = LDT(kb,0,32);
        const bf16x8 h1a = LDT(kb,1,0), h1b = LDT(kb,1,32);
        const bf16x8 h2a = LDT(kb,2,0), h2b = LDT(kb,2,32);
        const bf16x8 h3a = LDT(kb,3,0), h3b = LDT(kb,3,32);
        const bf16x8 h4a = LDT(kb,4,0), h4b = LDT(kb,4,32);
        const bf16x8 h5a = LDT(kb,5,0), h5b = LDT(kb,5,32);
        const bf16x8 h6a = LDT(kb,6,0), h6b = LDT(kb,6,32);
        const bf16x8 h7a = LDT(kb,7,0), h7b = LDT(kb,7,32);
        const bf16x8 l0a = LDT(lb,0,0), l0b = LDT(lb,0,32);
        const bf16x8 l1a = LDT(lb,1,0), l1b = LDT(lb,1,32);

#define QTILE(T, HA, HB, PA, PB) { \
        f32x4 c = {0.f, 0.f, 0.f, 0.f}; \
        c = __builtin_amdgcn_mfma_f32_16x16x32_bf16(HA, bqh0, c, 0, 0, 0); \
        c = __builtin_amdgcn_mfma_f32_16x16x32_bf16(HB, bqh1, c, 0, 0, 0); \
        c = __builtin_amdgcn_mfma_f32_16x16x32_bf16(HA, bql0, c, 0, 0, 0); \
        c = __builtin_amdgcn_mfma_f32_16x16x32_bf16(HB, bql1, c, 0, 0, 0); \
        c = __builtin_amdgcn_mfma_f32_16x16x32_bf16(PA, bqh0, c, 0, 0, 0); \
        c = __builtin_amdgcn_mfma_f32_16x16x32_bf16(PB, bqh1, c, 0, 0, 0); \
        c = c * 0.125f; \
        uint4 o; \
        o.x = f2ord(c[0]); o.y = f2ord(c[1]); o.z = f2ord(c[2]); o.w = f2ord(c[3]); \
        *(uint4*)(S + q15 * SSTR + w * 128 + (T) * 16 + quad * 4) = o; \
    }
        const bf16x8 l2a = LDT(lb,2,0), l2b = LDT(lb,2,32);
        QTILE(0, h0a, h0b, l0a, l0b)
        const bf16x8 l3a = LDT(lb,3,0), l3b = LDT(lb,3,32);
        QTILE(1, h1a, h1b, l1a, l1b)
        const bf16x8 l4a = LDT(lb,4,0), l4b = LDT(lb,4,32);
        QTILE(2, h2a, h2b, l2a, l2b)
        const bf16x8 l5a = LDT(lb,5,0), l5b = LDT(lb,5,32);
        QTILE(3, h3a, h3b, l3a, l3b)
        const bf16x8 l6a = LDT(lb,6,0), l6b = LDT(lb,6,32);
        QTILE(4, h4a, h4b, l4a, l4b)
        const bf16x8 l7a = LDT(lb,7,0), l7b = LDT(lb,7,32);
        QTILE(5, h5a, h5b, l5a, l5b)
        QTILE(6, h6a, h6b, l6a, l6b)
        QTILE(7, h7a, h7b, l7a, l7b)
#undef QTILE
#undef LDT
    }
    __syncthreads();   // full [16][2048] score matrix visible

    // ---- phase 2: one row per wave: select + softmax, in-place bf16 P ----
    const float invd = row_pass(S + w * SSTR, lane);
    __syncthreads();   // all P visible

    // ---- phase 3: PV via bf16 MFMA; ALL V loads + P reads hoisted ----
    {
        const unsigned short* vb = Vt + (size_t)bh * HDIM * S_LEN
                                 + (size_t)q15 * S_LEN + w * 128 + quad * 8;
        // hd stride = 16 * S_LEN elements; ks stride = 32 elements
#define LDV(KS, HT) (*(const bf16x8*)(vb + (size_t)(HT) * 16 * S_LEN + (KS) * 32))
        const bf16x8 v00 = LDV(0,0), v01 = LDV(0,1), v02 = LDV(0,2), v03 = LDV(0,3);
        const bf16x8 v10 = LDV(1,0), v11 = LDV(1,1), v12 = LDV(1,2), v13 = LDV(1,3);
        const bf16x8 v20 = LDV(2,0), v21 = LDV(2,1), v22 = LDV(2,2), v23 = LDV(2,3);
        const bf16x8 v30 = LDV(3,0), v31 = LDV(3,1), v32 = LDV(3,2), v33 = LDV(3,3);
#undef LDV
        const unsigned* Srow = S + q15 * SSTR + w * 128 + quad * 8;
        const uint4 a00 = *(const uint4*)(Srow + 0);
        const uint4 a01 = *(const uint4*)(Srow + 4);
        const uint4 a10 = *(const uint4*)(Srow + 32);
        const uint4 a11 = *(const uint4*)(Srow + 36);
        const uint4 a20 = *(const uint4*)(Srow + 64);
        const uint4 a21 = *(const uint4*)(Srow + 68);
        const uint4 a30 = *(const uint4*)(Srow + 96);
        const uint4 a31 = *(const uint4*)(Srow + 100);
        const bf16x8 ap0 = pack_hi8(a00, a01);
        const bf16x8 ap1 = pack_hi8(a10, a11);
        const bf16x8 ap2 = pack_hi8(a20, a21);
        const bf16x8 ap3 = pack_hi8(a30, a31);

        f32x4 o0 = {0.f,0.f,0.f,0.f}, o1 = {0.f,0.f,0.f,0.f};
        f32x4 o2 = {0.f,0.f,0.f,0.f}, o3 = {0.f,0.f,0.f,0.f};
        o0 = __builtin_amdgcn_mfma_f32_16x16x32_bf16(ap0, v00, o0, 0, 0, 0);
        o1 = __builtin_amdgcn_mfma_f32_16x16x32_bf16(ap0, v01, o1, 0, 0, 0);
        o2 = __builtin_amdgcn_mfma_f32_16x16x32_bf16(ap0, v02, o2, 0, 0, 0);
        o3 = __builtin_amdgcn_mfma_f32_16x16x32_bf16(ap0, v03, o3, 0, 0, 0);
        o0 = __builtin_amdgcn_mfma_f32_16x16x32_bf16(ap1, v10, o0, 0, 0, 0);
        o1 = __builtin_amdgcn_mfma_f32_16x16x32_bf16(ap1, v11, o1, 0, 0, 0);
        o2 = __builtin_amdgcn_mfma_f32_16x16x32_bf16(ap1, v12, o2, 0, 0, 0);
        o3 = __builtin_amdgcn_mfma_f32_16x16x32_bf16(ap1, v13, o3, 0, 0, 0);
        o0 = __builtin_amdgcn_mfma_f32_16x16x32_bf16(ap2, v20, o0, 0, 0, 0);
        o1 = __builtin_amdgcn_mfma_f32_16x16x32_bf16(ap2, v21, o1, 0, 0, 0);
        o2 = __builtin_amdgcn_mfma_f32_16x16x32_bf16(ap2, v22, o2, 0, 0, 0);
        o3 = __builtin_amdgcn_mfma_f32_16x16x32_bf16(ap2, v23, o3, 0, 0, 0);
        o0 = __builtin_amdgcn_mfma_f32_16x16x32_bf16(ap3, v30, o0, 0, 0, 0);
        o1 = __builtin_amdgcn_mfma_f32_16x16x32_bf16(ap3, v31, o1, 0, 0, 0);
        o2 = __builtin_amdgcn_mfma_f32_16x16x32_bf16(ap3, v32, o2, 0, 0, 0);
        o3 = __builtin_amdgcn_mfma_f32_16x16x32_bf16(ap3, v33, o3, 0, 0, 0);

        __syncthreads();   // all P reads done; score region dead -> Opart live
        // D[m=q][n=hd]: col=lane&15=hd-in-tile, row=quad*4+reg=q
        float* Ow = Opart + w * 1024 + quad * 4 * 64 + q15;
        Ow[0 * 64 +  0] = o0[0]; Ow[1 * 64 +  0] = o0[1];
        Ow[2 * 64 +  0] = o0[2]; Ow[3 * 64 +  0] = o0[3];
        Ow[0 * 64 + 16] = o1[0]; Ow[1 * 64 + 16] = o1[1];
        Ow[2 * 64 + 16] = o1[2]; Ow[3 * 64 + 16] = o1[3];
        Ow[0 * 64 + 32] = o2[0]; Ow[1 * 64 + 32] = o2[1];
        Ow[2 * 64 + 32] = o2[2]; Ow[3 * 64 + 32] = o2[3];
        Ow[0 * 64 + 48] = o3[0]; Ow[1 * 64 + 48] = o3[1];
        Ow[2 * 64 + 48] = o3[2]; Ow[3 * 64 + 48] = o3[3];
    }
    __syncthreads();

    // ---- final: wave w reduces 16 partials for row w, writes AO hi/lo ----
    {
        float s = 0.f;
#pragma unroll
        for (int ww = 0; ww < 16; ++ww)
            s += Opart[ww * 1024 + w * 64 + lane];
        const int b = bh >> 4, h = bh & 15;
        const float o = s * invd;
        const size_t i = ((size_t)(b * S_LEN + q0 + w)) * DMODEL + h * HDIM + lane;
        const unsigned short oh = f2bf(o);
        AOh[i] = oh; AOl[i] = f2bf(o - bf2f(oh));
    }
}

// ---------------------------------------------------------------------------
extern "C" void kernel_launch(void* const* d_in, const int* in_sizes, int n_in,
                              void* d_out, int out_size, void* d_ws, size_t ws_size,
                              hipStream_t stream)
{
    const float* X  = (const float*)d_in[0];
    const float* Wq = (const float*)d_in[1];
    const float* bq = (const float*)d_in[2];
    const float* Wk = (const float*)d_in[3];
    const float* bk = (const float*)d_in[4];
    const float* Wv = (const float*)d_in[5];
    const float* bv = (const float*)d_in[6];
    const float* Wo = (const float*)d_in[7];
    const float* bo = (const float*)d_in[8];

    char* p = (char*)d_ws;
    const size_t NEL = (size_t)BHC * S_LEN * HDIM;   // 4,194,304
    unsigned short* Q16h = (unsigned short*)p; p += NEL * 2;
    unsigned short* Q16l = (unsigned short*)p; p += NEL * 2;
    unsigned short* K16h = (unsigned short*)p; p += NEL * 2;
    unsigned short* K16l = (unsigned short*)p; p += NEL * 2;
    unsigned short* Vb16 = (unsigned short*)p; p += NEL * 2;
    unsigned short* Vt16 = (unsigned short*)p; p += NEL * 2;
    unsigned short* Xh   = (unsigned short*)p; p += NEL * 2;
    unsigned short* Xl   = (unsigned short*)p; p += NEL * 2;
    unsigned short* AOh  = (unsigned short*)p; p += NEL * 2;
    unsigned short* AOl  = (unsigned short*)p; p += NEL * 2;
    unsigned short* Wqh  = (unsigned short*)p; p += DMODEL * DMODEL * 2;
    unsigned short* Wql  = (unsigned short*)p; p += DMODEL * DMODEL * 2;
    unsigned short* Wkh  = (unsigned short*)p; p += DMODEL * DMODEL * 2;
    unsigned short* Wkl  = (unsigned short*)p; p += DMODEL * DMODEL * 2;
    unsigned short* Wvh  = (unsigned short*)p; p += DMODEL * DMODEL * 2;
    unsigned short* Wvl  = (unsigned short*)p; p += DMODEL * DMODEL * 2;
    unsigned short* Woh  = (unsigned short*)p; p += DMODEL * DMODEL * 2;
    unsigned short* Wol  = (unsigned short*)p; p += DMODEL * DMODEL * 2;

    const int attn_lds = 16 * SSTR * 4;   // 131,328 B -> 1 block/CU
    hipFuncSetAttribute((const void*)attn_kernel,
                        hipFuncAttributeMaxDynamicSharedMemorySize, attn_lds);

    const int X4 = (int)(NEL / 4);
    const int W4 = DMODEL * DMODEL / 4;

    // ---- input splits ----
    split32<<<(X4 + 255) / 256, 256, 0, stream>>>(X,  Xh,  Xl,  X4);
    split32<<<(W4 + 255) / 256, 256, 0, stream>>>(Wq, Wqh, Wql, W4);
    split32<<<(W4 + 255) / 256, 256, 0, stream>>>(Wk, Wkh, Wkl, W4);
    split32<<<(W4 + 255) / 256, 256, 0, stream>>>(Wv, Wvh, Wvl, W4);
    split32<<<(W4 + 255) / 256, 256, 0, stream>>>(Wo, Woh, Wol, W4);

    // ---- projections ----
    const dim3 ggrid(16, 32, 1);
    gemm_mfma<<<ggrid, 256, 0, stream>>>(Xh, Xl, Wqh, Wql, bq, Q16h, Q16l, 2);
    gemm_mfma<<<ggrid, 256, 0, stream>>>(Xh, Xl, Wkh, Wkl, bk, K16h, K16l, 2);
    gemm_mfma<<<ggrid, 256, 0, stream>>>(Xh, Xl, Wvh, Wvl, bv, Vb16, nullptr, 3);
    transpose_v16<<<dim3(32, 32, 1), 256, 0, stream>>>(Vb16, Vt16);

    // ---- fused attention (R19: deep register prefetch in QK^T / PV) ----
    attn_kernel<<<4096, 1024, attn_lds, stream>>>(Q16h, Q16l, K16h, K16l, Vt16, AOh, AOl);

    // ---- output projection ----
    gemm_mfma<<<ggrid, 256, 0, stream>>>(AOh, AOl, Woh, Wol, bo, d_out, nullptr, 0);
}